// Round 8
// baseline (234.379 us; speedup 1.0000x reference)
//
#include <hip/hip_runtime.h>
#include <hip/hip_bf16.h>

#define D 128
#define NBUCKET 64
#define BCAP 16384   // per-bucket edge capacity (mean 10k -> huge margin)

typedef __bf16 bf16x8 __attribute__((ext_vector_type(8)));
typedef float f32x4 __attribute__((ext_vector_type(4)));

// stored col j  <->  true col PI(j) = (j&7)*16 + (j>>3);  PI_inv(c) = (c&15)*8 + (c>>4)

// -------- combo (R7): weight-pack (blocks [0,128)) + bucketize (blocks [128,128+eab)) --------
// Counters (bcur/deghist/degcur) are zeroed by a prior 768B hipMemsetAsync.
__global__ void combo_kernel(const float* __restrict__ W1, const float* __restrict__ W2,
                             __bf16* __restrict__ pw,
                             const int* __restrict__ src, const int* __restrict__ dst,
                             int* __restrict__ bucket_cursor, int2* __restrict__ bucket_edges,
                             int e, int bucketW) {
    int b = blockIdx.x;
    int t = threadIdx.x;
    if (b < 128) {
        // ---- weight pack ----
        int tt = b * 256 + t;  // 0..32767
        int which = tt >> 14, idx = tt & 16383;
        const float* W = which ? W2 : W1;
        float w = W[idx];
        int k = idx >> 7, nn = idx & 127;
        int ks = which ? (((k & 15) << 3) | (k >> 4)) : k;  // PI_inv for layer 2
        int ntile = nn >> 4, nl = nn & 15;
        int kchunk = ks >> 5, quad = (ks >> 3) & 3, j = ks & 7;
        int o = (((ntile * 4 + kchunk) * 64 + quad * 16 + nl) << 3) + j;
        pw[(size_t)which * 16384 + o] = (__bf16)w;
        return;
    }
    // ---- bucketize ----
    __shared__ int hist[NBUCKET];
    __shared__ int gbase[NBUCKET];
    if (t < NBUCKET) hist[t] = 0;
    __syncthreads();
    int i0 = ((b - 128) * 256 + t) * 4;
    int sv[4], dv[4], bk[4], ls[4];
    int nv = 0;
    if (i0 + 4 <= e) {
        int4 s4 = *(const int4*)(src + i0);
        int4 d4 = *(const int4*)(dst + i0);
        sv[0] = s4.x; sv[1] = s4.y; sv[2] = s4.z; sv[3] = s4.w;
        dv[0] = d4.x; dv[1] = d4.y; dv[2] = d4.z; dv[3] = d4.w;
        nv = 4;
    } else {
        for (int i = i0; i < e; i++) { sv[nv] = src[i]; dv[nv] = dst[i]; nv++; }
    }
    for (int u = 0; u < nv; u++) {
        bk[u] = dv[u] / bucketW;
        ls[u] = atomicAdd(&hist[bk[u]], 1);
    }
    __syncthreads();
    if (t < NBUCKET) gbase[t] = atomicAdd(&bucket_cursor[t], hist[t]);
    __syncthreads();
    for (int u = 0; u < nv; u++) {
        int pos = bk[u] * BCAP + gbase[bk[u]] + ls[u];
        bucket_edges[pos] = make_int2(sv[u], dv[u]);
    }
}

// ---- shared gemm1 body: rows [r0base, ...), B (packed W1) staged in 32KB LDS ----
__device__ __forceinline__ void gemm1_body(char* smem, int t, int gbk,
                                           const float* __restrict__ X,
                                           const __bf16* __restrict__ PW,
                                           __bf16* __restrict__ Zs, int n) {
    bf16x8* sB = (bf16x8*)smem;  // 32 KB packed W1
    const bf16x8* PW8 = (const bf16x8*)PW;
#pragma unroll
    for (int i = 0; i < 8; i++) sB[t + 256 * i] = PW8[t + 256 * i];

    int wave = t >> 6, lane = t & 63;
    int qm = lane & 15, quad = lane >> 4;
    int r0 = gbk * 64 + wave * 16;
    int row = r0 + qm;
    bool valid = row < n;
    const float* xr = X + (size_t)row * D + quad * 8;

    bf16x8 ahi[4], alo[4];
#pragma unroll
    for (int c = 0; c < 4; c++) {
        float4 zf = {0.f, 0.f, 0.f, 0.f};
        float4 xa = valid ? ((const float4*)(xr + c * 32))[0] : zf;
        float4 xb = valid ? ((const float4*)(xr + c * 32))[1] : zf;
        float xs[8] = {xa.x, xa.y, xa.z, xa.w, xb.x, xb.y, xb.z, xb.w};
        bf16x8 h, l;
#pragma unroll
        for (int j = 0; j < 8; j++) {
            float v = xs[j];
            __bf16 hh = (__bf16)v;
            h[j] = hh;
            l[j] = (__bf16)(v - (float)hh);
        }
        ahi[c] = h; alo[c] = l;
    }

    f32x4 acc[8];
#pragma unroll
    for (int nt = 0; nt < 8; nt++) acc[nt] = (f32x4){0.f, 0.f, 0.f, 0.f};

    __syncthreads();

#pragma unroll
    for (int c = 0; c < 4; c++) {
#pragma unroll
        for (int nt = 0; nt < 8; nt++) {
            bf16x8 bb = sB[(nt * 4 + c) * 64 + lane];
            acc[nt] = __builtin_amdgcn_mfma_f32_16x16x32_bf16(ahi[c], bb, acc[nt], 0, 0, 0);
            acc[nt] = __builtin_amdgcn_mfma_f32_16x16x32_bf16(alo[c], bb, acc[nt], 0, 0, 0);
        }
    }

    // C/D: true col = nt*16+qm -> stored col qm*8+nt; row = quad*4+reg
#pragma unroll
    for (int reg = 0; reg < 4; reg++) {
        int orow = r0 + quad * 4 + reg;
        if (orow < n) {
            bf16x8 o;
#pragma unroll
            for (int nt = 0; nt < 8; nt++) o[nt] = (__bf16)acc[nt][reg];
            *(bf16x8*)(Zs + (size_t)orow * D + qm * 8) = o;
        }
    }
}

// ------- mega_a (R7): count2 (blocks [0,256)) + gemm1 half-1 (blocks [256, 256+gba)) -------
// count2: LDS-binned degree count; counts, dinv, block edge-sum, degree histogram.
__global__ void mega_a_kernel(const int2* __restrict__ bucket_edges,
                              const int* __restrict__ bucket_cursor,
                              int* __restrict__ counts, float* __restrict__ dinv,
                              int* __restrict__ partial, int* __restrict__ deghist,
                              const float* __restrict__ X, const __bf16* __restrict__ PW,
                              __bf16* __restrict__ Zs,
                              int n, int bucketW, int subW) {
    __shared__ __align__(16) char smem[32768];
    int b = blockIdx.x, t = threadIdx.x;
    if (b < 256) {
        int* bins = (int*)smem;       // 400
        int* sm   = bins + 400;       // 256
        int* hb   = sm + 256;         // 64
        int bk = b >> 2, j = b & 3;
        int ns = bk * bucketW + j * subW;
        int be = min((bk + 1) * bucketW, n);
        int ne = min(ns + subW, be);
        int w = ne - ns;
        if (w <= 0) { if (t == 0) partial[b] = 0; return; }
        for (int i = t; i < w; i += 256) bins[i] = 0;
        if (t < 64) hb[t] = 0;
        __syncthreads();
        int m = bucket_cursor[bk];
        const int2* eb = bucket_edges + (size_t)bk * BCAP;
        for (int i = t; i < m; i += 256) {
            int d = eb[i].y;
            if (d >= ns && d < ne) atomicAdd(&bins[d - ns], 1);
        }
        __syncthreads();
        int s = 0;
        for (int i = t; i < w; i += 256) {
            int c = bins[i];
            counts[ns + i] = c;
            dinv[ns + i] = rsqrtf((float)(c + 1));  // +1 self loop
            atomicAdd(&hb[min(c, 63)], 1);
            s += c;
        }
        sm[t] = s; __syncthreads();
        for (int off = 128; off > 0; off >>= 1) { if (t < off) sm[t] += sm[t + off]; __syncthreads(); }
        if (t == 0) partial[b] = sm[0];
        if (t < 64 && hb[t]) atomicAdd(&deghist[t], hb[t]);
        return;
    }
    gemm1_body(smem, t, b - 256, X, PW, Zs, n);
}

// ------- mega_b (R7): scanfill (blocks [0,256)) + gemm1 half-2 (rest) -------
// scanfill: inline exclusive scans of partial[256]/deghist[64] (R6 form), local row_ptr,
// CSR scatter, degree-sorted order scatter.
__global__ void mega_b_kernel(const int2* __restrict__ bucket_edges,
                              const int* __restrict__ bucket_cursor,
                              const int* __restrict__ counts,
                              const int* __restrict__ partial,
                              const int* __restrict__ deghist,
                              int* __restrict__ row_ptr, int* __restrict__ csr,
                              int* __restrict__ degcur, int* __restrict__ order,
                              const float* __restrict__ X, const __bf16* __restrict__ PW,
                              __bf16* __restrict__ Zs,
                              int n, int bucketW, int subW, int gba) {
    __shared__ __align__(16) char smem[32768];
    int b = blockIdx.x, t = threadIdx.x;
    if (b < 256) {
        int* cur  = (int*)smem;       // 400
        int* sm   = cur + 400;        // 256
        int* hb2  = sm + 256;         // 64
        int* gb2  = hb2 + 64;         // 64
        int* dgex = gb2 + 64;         // 64
        int* pexs = dgex + 64;        // 1
        int bk = b >> 2, j = b & 3;
        int ns = bk * bucketW + j * subW;
        int be = min((bk + 1) * bucketW, n);
        int ne = min(ns + subW, be);
        int w = ne - ns;
        if (w <= 0) return;
        // ---- inline exclusive scan of partial[256]; capture this block's base ----
        int pv = partial[t];
        sm[t] = pv; __syncthreads();
        for (int off = 1; off < 256; off <<= 1) {
            int u = (t >= off) ? sm[t - off] : 0;
            __syncthreads();
            sm[t] += u;
            __syncthreads();
        }
        if (t == b) pexs[0] = sm[t] - pv;
        __syncthreads();
        int pbase = pexs[0];
        // ---- inline exclusive scan of deghist[64] ----
        int dh = (t < 64) ? deghist[t] : 0;
        sm[t] = dh; __syncthreads();
        for (int off = 1; off < 64; off <<= 1) {
            int u = (t >= off && t < 64) ? sm[t - off] : 0;
            __syncthreads();
            if (t < 64) sm[t] += u;
            __syncthreads();
        }
        if (t < 64) { dgex[t] = sm[t] - dh; hb2[t] = 0; }
        __syncthreads();
        // ---- counts scan (local row_ptr) ----
        int i0 = t * 2;
        int c0 = (i0 < w) ? counts[ns + i0] : 0;
        int c1 = (i0 + 1 < w) ? counts[ns + i0 + 1] : 0;
        sm[t] = c0 + c1; __syncthreads();
        int own = c0 + c1;
        for (int off = 1; off < 256; off <<= 1) {
            int u = (t >= off) ? sm[t - off] : 0;
            __syncthreads();
            sm[t] += u;
            __syncthreads();
        }
        int base = pbase + sm[t] - own;
        if (i0 < w)     { row_ptr[ns + i0] = base;          cur[i0] = base; }
        if (i0 + 1 < w) { row_ptr[ns + i0 + 1] = base + c0; cur[i0 + 1] = base + c0; }
        // degree-order: local ranks within block per bin
        int bin0 = min(c0, 63), bin1 = min(c1, 63);
        int r0 = (i0 < w) ? atomicAdd(&hb2[bin0], 1) : 0;
        int r1 = (i0 + 1 < w) ? atomicAdd(&hb2[bin1], 1) : 0;
        __syncthreads();
        if (t < 64 && hb2[t]) gb2[t] = atomicAdd(&degcur[t], hb2[t]);
        __syncthreads();
        if (i0 < w)     order[dgex[bin0] + gb2[bin0] + r0] = ns + i0;
        if (i0 + 1 < w) order[dgex[bin1] + gb2[bin1] + r1] = ns + i0 + 1;
        __syncthreads();
        int m = bucket_cursor[bk];
        const int2* eb = bucket_edges + (size_t)bk * BCAP;
        for (int i = t; i < m; i += 256) {
            int2 ed = eb[i];
            if (ed.y >= ns && ed.y < ne) {
                int pos = atomicAdd(&cur[ed.y - ns], 1);
                csr[pos] = ed.x;
            }
        }
        return;
    }
    gemm1_body(smem, t, gba + (b - 256), X, PW, Zs, n);
}

// ------- fused agg1 + gemm2: block owns 32 consecutive order-slots, HEAVY-FIRST. -------
// Phase A: H = relu(dinv^2*Z1[v] + sum w*Z1[s] + b1) -> LDS (XOR-swizzled 16B slots),
//   4-deep csr prefetch breaking the csr->row serial latency chain (R3 form, 43.6 us).
// Phase B: Z2'[v] = dinv[v] * (H @ W2), W2 staged in 4 x 8KB rounds (16KB LDS total).
__global__ void agg1_gemm2_kernel(const __bf16* __restrict__ Zs, const int* __restrict__ row_ptr,
                                  const int* __restrict__ counts, const int* __restrict__ csr,
                                  const float* __restrict__ dinv, const float* __restrict__ bias,
                                  const __bf16* __restrict__ PW, const int* __restrict__ order,
                                  __bf16* __restrict__ Z2, int n) {
    __shared__ __align__(16) __bf16 sH[32 * 128];  // 8 KB
    __shared__ bf16x8 sBp[512];                    // 8 KB (one k-chunk of packed W2)
    int t = threadIdx.x;  // 0..127
    const bf16x8* PW8 = (const bf16x8*)PW;

    int gbase = blockIdx.x * 32;
    int grp = t >> 4, c = t & 15;

    // hoist bias for this lane's 8 stored cols (true col j*16+c)
    float bs[8];
#pragma unroll
    for (int j = 0; j < 8; j++) bs[j] = bias[j * 16 + c];

    const bf16x8* Z8 = (const bf16x8*)Zs;
    for (int r = 0; r < 4; r++) {
        int lr = r * 8 + grp;           // local row 0..31
        int idx = gbase + lr;
        bf16x8 o = {};
        if (idx < n) {
            int v = order[(n - 1) - idx];   // heavy-first
            float dv = dinv[v];
            bf16x8 zc = Z8[(size_t)v * 16 + c];
            float sw = dv * dv;
            float acc[8];
#pragma unroll
            for (int j = 0; j < 8; j++) acc[j] = (float)zc[j] * sw;
            int start = row_ptr[v], cnt = counts[v];
            int i = 0;
            if (cnt >= 4) {
                int s0 = csr[start], s1 = csr[start + 1];
                int s2 = csr[start + 2], s3 = csr[start + 3];
                for (; i + 8 <= cnt; i += 4) {
                    int t0 = csr[start + i + 4], t1 = csr[start + i + 5];
                    int t2 = csr[start + i + 6], t3 = csr[start + i + 7];
                    bf16x8 m0 = Z8[(size_t)s0 * 16 + c];
                    bf16x8 m1 = Z8[(size_t)s1 * 16 + c];
                    bf16x8 m2 = Z8[(size_t)s2 * 16 + c];
                    bf16x8 m3 = Z8[(size_t)s3 * 16 + c];
                    float w0 = dinv[s0] * dv, w1 = dinv[s1] * dv;
                    float w2 = dinv[s2] * dv, w3 = dinv[s3] * dv;
#pragma unroll
                    for (int j = 0; j < 8; j++) acc[j] = fmaf(w0, (float)m0[j], acc[j]);
#pragma unroll
                    for (int j = 0; j < 8; j++) acc[j] = fmaf(w1, (float)m1[j], acc[j]);
#pragma unroll
                    for (int j = 0; j < 8; j++) acc[j] = fmaf(w2, (float)m2[j], acc[j]);
#pragma unroll
                    for (int j = 0; j < 8; j++) acc[j] = fmaf(w3, (float)m3[j], acc[j]);
                    s0 = t0; s1 = t1; s2 = t2; s3 = t3;
                }
                {   // drain the prefetched quad
                    bf16x8 m0 = Z8[(size_t)s0 * 16 + c];
                    bf16x8 m1 = Z8[(size_t)s1 * 16 + c];
                    bf16x8 m2 = Z8[(size_t)s2 * 16 + c];
                    bf16x8 m3 = Z8[(size_t)s3 * 16 + c];
                    float w0 = dinv[s0] * dv, w1 = dinv[s1] * dv;
                    float w2 = dinv[s2] * dv, w3 = dinv[s3] * dv;
#pragma unroll
                    for (int j = 0; j < 8; j++) acc[j] = fmaf(w0, (float)m0[j], acc[j]);
#pragma unroll
                    for (int j = 0; j < 8; j++) acc[j] = fmaf(w1, (float)m1[j], acc[j]);
#pragma unroll
                    for (int j = 0; j < 8; j++) acc[j] = fmaf(w2, (float)m2[j], acc[j]);
#pragma unroll
                    for (int j = 0; j < 8; j++) acc[j] = fmaf(w3, (float)m3[j], acc[j]);
                    i += 4;
                }
            }
            for (; i < cnt; i++) {
                int s0 = csr[start + i];
                float w0 = dinv[s0] * dv;
                bf16x8 m0 = Z8[(size_t)s0 * 16 + c];
#pragma unroll
                for (int j = 0; j < 8; j++) acc[j] = fmaf(w0, (float)m0[j], acc[j]);
            }
#pragma unroll
            for (int j = 0; j < 8; j++) o[j] = (__bf16)fmaxf(acc[j] + bs[j], 0.f);
        }
        // swizzled 16B-slot write: slot c -> c ^ (lr&7)
        *(bf16x8*)(sH + lr * 128 + ((c ^ (lr & 7)) << 3)) = o;
    }

    // ---- phase B: 4 rounds; each stages 8KB of W2 (k-chunk cc) then 8 MFMAs ----
    int wave = t >> 6, lane = t & 63;
    int qm = lane & 15, quad = lane >> 4;
    int lrow = wave * 16 + qm;

    f32x4 acc[8];
#pragma unroll
    for (int nt = 0; nt < 8; nt++) acc[nt] = (f32x4){0.f, 0.f, 0.f, 0.f};

#pragma unroll
    for (int cc = 0; cc < 4; cc++) {
        __syncthreads();  // round cc-1 reads done (and, at cc=0, all sH writes visible)
#pragma unroll
        for (int i = 0; i < 4; i++) {
            int idx = i * 128 + t;  // 0..511
            sBp[idx] = PW8[((idx >> 6) * 4 + cc) * 64 + (idx & 63)];
        }
        // A-fragment for this k-chunk from swizzled sH (overlaps with sBp stage)
        int slot = quad + cc * 4;  // 16B slot index within the 256B row
        bf16x8 a = *(const bf16x8*)(sH + lrow * 128 + ((slot ^ (lrow & 7)) << 3));
        __syncthreads();  // sBp visible
#pragma unroll
        for (int nt = 0; nt < 8; nt++) {
            bf16x8 bb = sBp[nt * 64 + lane];
            acc[nt] = __builtin_amdgcn_mfma_f32_16x16x32_bf16(a, bb, acc[nt], 0, 0, 0);
        }
    }

    // C/D: true col = nt*16+qm -> stored col qm*8+nt; local row = wave*16 + quad*4 + reg
#pragma unroll
    for (int reg = 0; reg < 4; reg++) {
        int lrr = wave * 16 + quad * 4 + reg;
        int gidx = gbase + lrr;
        if (gidx < n) {
            int v = order[(n - 1) - gidx];  // heavy-first (must match phase A mapping)
            float sc = dinv[v];  // prescale: Z2' = dinv[v] * Z2
            bf16x8 o;
#pragma unroll
            for (int nt = 0; nt < 8; nt++) o[nt] = (__bf16)(acc[nt][reg] * sc);
            *(bf16x8*)(Z2 + (size_t)v * D + qm * 8) = o;
        }
    }
}

// ------- agg2 + fc fused (heavy-first, Z2 PRESCALED by dinv): -------
// out[v] = relu(dinv_v * (sum_s Z2'[s] + Z2'[v]) + b2) @ Wfc + bfc
__global__ void agg2_fc_kernel(const __bf16* __restrict__ Zs, const int* __restrict__ row_ptr,
                               const int* __restrict__ counts, const int* __restrict__ csr,
                               const float* __restrict__ dinv, const float* __restrict__ bias,
                               const float* __restrict__ Wfc, const float* __restrict__ bfc,
                               const int* __restrict__ order, float* __restrict__ out, int n) {
    int t = blockIdx.x * 256 + threadIdx.x;
    int idx = t >> 4, c = t & 15;
    if (idx >= n) return;
    int v = order[(n - 1) - idx];   // heavy-first
    float dv = dinv[v];
    const bf16x8* Z8 = (const bf16x8*)Zs;
    bf16x8 zc = Z8[(size_t)v * 16 + c];  // self term: dinv_v^2 Z2[v] = dinv_v * Z2'[v]
    float acc[8];
#pragma unroll
    for (int j = 0; j < 8; j++) acc[j] = (float)zc[j];
    int start = row_ptr[v], cnt = counts[v];
    int i = 0;
    if (cnt >= 4) {
        int s0 = csr[start], s1 = csr[start + 1];
        int s2 = csr[start + 2], s3 = csr[start + 3];
        for (; i + 8 <= cnt; i += 4) {
            int t0 = csr[start + i + 4], t1 = csr[start + i + 5];
            int t2 = csr[start + i + 6], t3 = csr[start + i + 7];
            bf16x8 m0 = Z8[(size_t)s0 * 16 + c];
            bf16x8 m1 = Z8[(size_t)s1 * 16 + c];
            bf16x8 m2 = Z8[(size_t)s2 * 16 + c];
            bf16x8 m3 = Z8[(size_t)s3 * 16 + c];
#pragma unroll
            for (int j = 0; j < 8; j++) acc[j] += (float)m0[j];
#pragma unroll
            for (int j = 0; j < 8; j++) acc[j] += (float)m1[j];
#pragma unroll
            for (int j = 0; j < 8; j++) acc[j] += (float)m2[j];
#pragma unroll
            for (int j = 0; j < 8; j++) acc[j] += (float)m3[j];
            s0 = t0; s1 = t1; s2 = t2; s3 = t3;
        }
        {
            bf16x8 m0 = Z8[(size_t)s0 * 16 + c];
            bf16x8 m1 = Z8[(size_t)s1 * 16 + c];
            bf16x8 m2 = Z8[(size_t)s2 * 16 + c];
            bf16x8 m3 = Z8[(size_t)s3 * 16 + c];
#pragma unroll
            for (int j = 0; j < 8; j++) acc[j] += (float)m0[j];
#pragma unroll
            for (int j = 0; j < 8; j++) acc[j] += (float)m1[j];
#pragma unroll
            for (int j = 0; j < 8; j++) acc[j] += (float)m2[j];
#pragma unroll
            for (int j = 0; j < 8; j++) acc[j] += (float)m3[j];
            i += 4;
        }
    }
    for (; i < cnt; i++) {
        int s0 = csr[start + i];
        bf16x8 m0 = Z8[(size_t)s0 * 16 + c];
#pragma unroll
        for (int j = 0; j < 8; j++) acc[j] += (float)m0[j];
    }
    float a0 = 0.f, a1 = 0.f;
#pragma unroll
    for (int j = 0; j < 8; j++) {
        int p = j * 16 + c;  // true col
        float hj = fmaxf(fmaf(dv, acc[j], bias[p]), 0.f);
        a0 = fmaf(hj, Wfc[p * 2], a0);
        a1 = fmaf(hj, Wfc[p * 2 + 1], a1);
    }
#pragma unroll
    for (int off = 8; off > 0; off >>= 1) {
        a0 += __shfl_down(a0, off, 16);
        a1 += __shfl_down(a1, off, 16);
    }
    if (c == 0) {
        out[(size_t)v * 2 + 0] = a0 + bfc[0];
        out[(size_t)v * 2 + 1] = a1 + bfc[1];
    }
}

// ---------------- launch ----------------

extern "C" void kernel_launch(void* const* d_in, const int* in_sizes, int n_in,
                              void* d_out, int out_size, void* d_ws, size_t ws_size,
                              hipStream_t stream) {
    const float* x   = (const float*)d_in[0];
    const int*   ei  = (const int*)d_in[1];
    const float* W1  = (const float*)d_in[2];
    const float* b1  = (const float*)d_in[3];
    const float* W2  = (const float*)d_in[4];
    const float* b2  = (const float*)d_in[5];
    const float* Wfc = (const float*)d_in[6];
    const float* bfc = (const float*)d_in[7];
    float* out = (float*)d_out;

    int n = in_sizes[0] / D;   // 100000
    int e = in_sizes[1] / 2;   // 640000
    const int* src = ei;
    const int* dst = ei + e;

    int bucketW = (n + NBUCKET - 1) / NBUCKET;   // 1563
    int subW = (bucketW + 3) / 4;                // 391 (fits bins[400])

    // workspace layout (16B-aligned at these sizes)
    char* ws = (char*)d_ws;
    size_t nb = (size_t)n * 4;
    int*    counts  = (int*)(ws);
    float*  dinv    = (float*)(ws + nb);
    int*    rowptr  = (int*)(ws + 2 * nb);
    int*    partial = (int*)(ws + 3 * nb);                    // 1024 B
    int*    bcur    = (int*)(ws + 3 * nb + 1024);             // 256 B
    int*    deghist = (int*)(ws + 3 * nb + 1280);             // 256 B
    int*    degcur  = (int*)(ws + 3 * nb + 1536);             // 256 B (+256 pad)
    int*    order   = (int*)(ws + 3 * nb + 2048);             // n*4
    int2*   bedges  = (int2*)(ws + 4 * nb + 2048);            // 8 MB
    size_t  off1    = 4 * nb + 2048 + (size_t)NBUCKET * BCAP * 8;
    int*    csr     = (int*)(ws + off1);                      // e*4
    __bf16* pw      = (__bf16*)(ws + off1 + (size_t)e * 4);   // 64 KB packed (W1|W2)
    __bf16* z1      = (__bf16*)(ws + off1 + (size_t)e * 4 + 65536);
    __bf16* z2      = z1 + (size_t)n * D;

    int eab = ((e + 3) / 4 + 255) / 256;       // bucketize blocks (625)
    int gb  = (n + 63) / 64;                   // gemm blocks (1563)
    int gba = (gb + 1) / 2;                    // gemm half-1 blocks (782)
    int gbb = gb - gba;                        // gemm half-2 blocks (781)
    int gb2 = (n + 31) / 32;                   // fused agg1+gemm2 blocks (3125)
    int ab  = ((n * 16) + 255) / 256;          // agg blocks (6250)

    // zero bcur(256B) + deghist(256B) + degcur(256B) = 768B contiguous
    hipMemsetAsync(ws + 3 * nb + 1024, 0, 768, stream);
    combo_kernel<<<128 + eab, 256, 0, stream>>>(W1, W2, pw, src, dst, bcur, bedges,
                                                e, bucketW);
    mega_a_kernel<<<256 + gba, 256, 0, stream>>>(bedges, bcur, counts, dinv, partial,
                                                 deghist, x, pw, z1, n, bucketW, subW);
    mega_b_kernel<<<256 + gbb, 256, 0, stream>>>(bedges, bcur, counts, partial, deghist,
                                                 rowptr, csr, degcur, order, x, pw, z1,
                                                 n, bucketW, subW, gba);
    agg1_gemm2_kernel<<<gb2, 128, 0, stream>>>(z1, rowptr, counts, csr, dinv, b1,
                                               pw + 16384, order, z2, n);
    agg2_fc_kernel<<<ab, 256, 0, stream>>>(z2, rowptr, counts, csr, dinv, b2, Wfc, bfc,
                                           order, out, n);
}

// Round 9
// 233.487 us; speedup vs baseline: 1.0038x; 1.0038x over previous
//
#include <hip/hip_runtime.h>
#include <hip/hip_bf16.h>

#define D 128
#define NBUCKET 64
#define BCAP 16384   // per-bucket edge capacity (mean 10k -> huge margin)

typedef __bf16 bf16x8 __attribute__((ext_vector_type(8)));
typedef float f32x4 __attribute__((ext_vector_type(4)));

// stored col j  <->  true col PI(j) = (j&7)*16 + (j>>3);  PI_inv(c) = (c&15)*8 + (c>>4)

// -------- prep: pack weights + zero bucket cursors + degree hist + degree cursors --------
__global__ void prep_kernel(const float* __restrict__ W1, const float* __restrict__ W2,
                            __bf16* __restrict__ pw, int* __restrict__ bucket_cursor,
                            int* __restrict__ deghist, int* __restrict__ degcur) {
    int b = blockIdx.x;
    if (b < 128) {
        int t = b * 256 + threadIdx.x;  // 0..32767
        int which = t >> 14, idx = t & 16383;
        const float* W = which ? W2 : W1;
        float w = W[idx];
        int k = idx >> 7, nn = idx & 127;
        int ks = which ? (((k & 15) << 3) | (k >> 4)) : k;  // PI_inv for layer 2
        int ntile = nn >> 4, nl = nn & 15;
        int kchunk = ks >> 5, quad = (ks >> 3) & 3, j = ks & 7;
        int o = (((ntile * 4 + kchunk) * 64 + quad * 16 + nl) << 3) + j;
        pw[(size_t)which * 16384 + o] = (__bf16)w;
    } else {
        int t = threadIdx.x;
        if (t < NBUCKET) bucket_cursor[t] = 0;
        else if (t < 128) deghist[t - 64] = 0;
        else if (t < 192) degcur[t - 128] = 0;   // degcur starts at 0 (within-bin cursor)
    }
}

// ------- mega1: gemm1 (blocks [0,gb)) + edge bucketize (blocks [gb, gb+eab)) -------
// gemm1: Zs = X(fp32) @ W1bf16, A split 2-term, B staged in LDS (proven R10 form).
__global__ void mega1_kernel(const float* __restrict__ X, const __bf16* __restrict__ PW,
                             __bf16* __restrict__ Zs, int nrows, int gb,
                             const int* __restrict__ src, const int* __restrict__ dst,
                             int* __restrict__ bucket_cursor, int2* __restrict__ bucket_edges,
                             int e, int bucketW) {
    __shared__ __align__(16) char smem[32768];
    int t = threadIdx.x;
    int b = blockIdx.x;
    if (b >= gb) {
        // ---- bucketize path ----
        int* hist = (int*)smem;          // 64
        int* gbase = hist + 64;          // 64
        if (t < NBUCKET) hist[t] = 0;
        __syncthreads();
        int i0 = ((b - gb) * 256 + t) * 4;
        int sv[4], dv[4], bk[4], ls[4];
        int nv = 0;
        if (i0 + 4 <= e) {
            int4 s4 = *(const int4*)(src + i0);
            int4 d4 = *(const int4*)(dst + i0);
            sv[0] = s4.x; sv[1] = s4.y; sv[2] = s4.z; sv[3] = s4.w;
            dv[0] = d4.x; dv[1] = d4.y; dv[2] = d4.z; dv[3] = d4.w;
            nv = 4;
        } else {
            for (int i = i0; i < e; i++) { sv[nv] = src[i]; dv[nv] = dst[i]; nv++; }
        }
        for (int u = 0; u < nv; u++) {
            bk[u] = dv[u] / bucketW;
            ls[u] = atomicAdd(&hist[bk[u]], 1);
        }
        __syncthreads();
        if (t < NBUCKET) gbase[t] = atomicAdd(&bucket_cursor[t], hist[t]);
        __syncthreads();
        for (int u = 0; u < nv; u++) {
            int pos = bk[u] * BCAP + gbase[bk[u]] + ls[u];
            bucket_edges[pos] = make_int2(sv[u], dv[u]);
        }
        return;
    }
    // ---- gemm1 path ----
    bf16x8* sB = (bf16x8*)smem;  // 32 KB packed W
    const bf16x8* PW8 = (const bf16x8*)PW;
#pragma unroll
    for (int i = 0; i < 8; i++) sB[t + 256 * i] = PW8[t + 256 * i];

    int wave = t >> 6, lane = t & 63;
    int qm = lane & 15, quad = lane >> 4;
    int r0 = b * 64 + wave * 16;
    int row = r0 + qm;
    bool valid = row < nrows;
    const float* xr = X + (size_t)row * D + quad * 8;

    bf16x8 ahi[4], alo[4];
#pragma unroll
    for (int c = 0; c < 4; c++) {
        float4 zf = {0.f, 0.f, 0.f, 0.f};
        float4 xa = valid ? ((const float4*)(xr + c * 32))[0] : zf;
        float4 xb = valid ? ((const float4*)(xr + c * 32))[1] : zf;
        float xs[8] = {xa.x, xa.y, xa.z, xa.w, xb.x, xb.y, xb.z, xb.w};
        bf16x8 h, l;
#pragma unroll
        for (int j = 0; j < 8; j++) {
            float v = xs[j];
            __bf16 hh = (__bf16)v;
            h[j] = hh;
            l[j] = (__bf16)(v - (float)hh);
        }
        ahi[c] = h; alo[c] = l;
    }

    f32x4 acc[8];
#pragma unroll
    for (int nt = 0; nt < 8; nt++) acc[nt] = (f32x4){0.f, 0.f, 0.f, 0.f};

    __syncthreads();

#pragma unroll
    for (int c = 0; c < 4; c++) {
#pragma unroll
        for (int nt = 0; nt < 8; nt++) {
            bf16x8 bb = sB[(nt * 4 + c) * 64 + lane];
            acc[nt] = __builtin_amdgcn_mfma_f32_16x16x32_bf16(ahi[c], bb, acc[nt], 0, 0, 0);
            acc[nt] = __builtin_amdgcn_mfma_f32_16x16x32_bf16(alo[c], bb, acc[nt], 0, 0, 0);
        }
    }

    // C/D: true col = nt*16+qm -> stored col qm*8+nt; row = quad*4+reg
#pragma unroll
    for (int reg = 0; reg < 4; reg++) {
        int orow = r0 + quad * 4 + reg;
        if (orow < nrows) {
            bf16x8 o;
#pragma unroll
            for (int nt = 0; nt < 8; nt++) o[nt] = (__bf16)acc[nt][reg];
            *(bf16x8*)(Zs + (size_t)orow * D + qm * 8) = o;
        }
    }
}

// ------- count2: LDS-binned degree count; writes counts, dinv, block edge-sum, -------
// ------- and accumulates the global degree histogram (64 bins, block-privatized). -------
__global__ void count2_kernel(const int2* __restrict__ bucket_edges,
                              const int* __restrict__ bucket_cursor,
                              int* __restrict__ counts, float* __restrict__ dinv,
                              int* __restrict__ partial, int* __restrict__ deghist,
                              int n, int bucketW, int subW) {
    __shared__ int bins[400];
    __shared__ int sm[256];
    __shared__ int hb[64];
    int b = blockIdx.x, t = threadIdx.x;
    int bk = b >> 2, j = b & 3;
    int ns = bk * bucketW + j * subW;
    int be = min((bk + 1) * bucketW, n);
    int ne = min(ns + subW, be);
    int w = ne - ns;
    if (w <= 0) { if (t == 0) partial[b] = 0; return; }
    for (int i = t; i < w; i += 256) bins[i] = 0;
    if (t < 64) hb[t] = 0;
    __syncthreads();
    int m = bucket_cursor[bk];
    const int2* eb = bucket_edges + (size_t)bk * BCAP;
    for (int i = t; i < m; i += 256) {
        int d = eb[i].y;
        if (d >= ns && d < ne) atomicAdd(&bins[d - ns], 1);
    }
    __syncthreads();
    int s = 0;
    for (int i = t; i < w; i += 256) {
        int c = bins[i];
        counts[ns + i] = c;
        dinv[ns + i] = rsqrtf((float)(c + 1));  // +1 self loop
        atomicAdd(&hb[min(c, 63)], 1);
        s += c;
    }
    sm[t] = s; __syncthreads();
    for (int off = 128; off > 0; off >>= 1) { if (t < off) sm[t] += sm[t + off]; __syncthreads(); }
    if (t == 0) partial[b] = sm[0];
    if (t < 64 && hb[t]) atomicAdd(&deghist[t], hb[t]);
}

// ------- scan_fill (scan_top folded in): each block redundantly computes the -------
// ------- exclusive scans of partial[256] and deghist[64] in LDS (~1 us, parallel  -------
// ------- across blocks) -> one fewer serial dispatch. degcur starts at 0 and is   -------
// ------- only the within-bin cross-block cursor; order idx = dgex[bin]+base+rank. -------
__global__ void scanfill_kernel(const int2* __restrict__ bucket_edges,
                                const int* __restrict__ bucket_cursor,
                                const int* __restrict__ counts,
                                const int* __restrict__ partial,
                                const int* __restrict__ deghist,
                                int* __restrict__ row_ptr, int* __restrict__ csr,
                                int* __restrict__ degcur, int* __restrict__ order,
                                int n, int bucketW, int subW) {
    __shared__ int cur[400];
    __shared__ int sm[256];
    __shared__ int hb2[64];
    __shared__ int gb2[64];
    __shared__ int dgex[64];
    __shared__ int pexs;
    int b = blockIdx.x, t = threadIdx.x;
    int bk = b >> 2, j = b & 3;
    int ns = bk * bucketW + j * subW;
    int be = min((bk + 1) * bucketW, n);
    int ne = min(ns + subW, be);
    int w = ne - ns;
    if (w <= 0) return;
    // ---- inline exclusive scan of partial[256]; capture this block's base ----
    int pv = partial[t];
    sm[t] = pv; __syncthreads();
    for (int off = 1; off < 256; off <<= 1) {
        int u = (t >= off) ? sm[t - off] : 0;
        __syncthreads();
        sm[t] += u;
        __syncthreads();
    }
    if (t == b) pexs = sm[t] - pv;
    __syncthreads();
    int pbase = pexs;
    // ---- inline exclusive scan of deghist[64] ----
    int dh = (t < 64) ? deghist[t] : 0;
    sm[t] = dh; __syncthreads();
    for (int off = 1; off < 64; off <<= 1) {
        int u = (t >= off && t < 64) ? sm[t - off] : 0;
        __syncthreads();
        if (t < 64) sm[t] += u;
        __syncthreads();
    }
    if (t < 64) { dgex[t] = sm[t] - dh; hb2[t] = 0; }
    __syncthreads();
    // ---- counts scan (local row_ptr) ----
    int i0 = t * 2;
    int c0 = (i0 < w) ? counts[ns + i0] : 0;
    int c1 = (i0 + 1 < w) ? counts[ns + i0 + 1] : 0;
    sm[t] = c0 + c1; __syncthreads();
    int own = c0 + c1;
    for (int off = 1; off < 256; off <<= 1) {
        int u = (t >= off) ? sm[t - off] : 0;
        __syncthreads();
        sm[t] += u;
        __syncthreads();
    }
    int base = pbase + sm[t] - own;
    if (i0 < w)     { row_ptr[ns + i0] = base;          cur[i0] = base; }
    if (i0 + 1 < w) { row_ptr[ns + i0 + 1] = base + c0; cur[i0 + 1] = base + c0; }
    // degree-order: local ranks within block per bin
    int bin0 = min(c0, 63), bin1 = min(c1, 63);
    int r0 = (i0 < w) ? atomicAdd(&hb2[bin0], 1) : 0;
    int r1 = (i0 + 1 < w) ? atomicAdd(&hb2[bin1], 1) : 0;
    __syncthreads();
    if (t < 64 && hb2[t]) gb2[t] = atomicAdd(&degcur[t], hb2[t]);
    __syncthreads();
    if (i0 < w)     order[dgex[bin0] + gb2[bin0] + r0] = ns + i0;
    if (i0 + 1 < w) order[dgex[bin1] + gb2[bin1] + r1] = ns + i0 + 1;
    __syncthreads();
    int m = bucket_cursor[bk];
    const int2* eb = bucket_edges + (size_t)bk * BCAP;
    for (int i = t; i < m; i += 256) {
        int2 ed = eb[i];
        if (ed.y >= ns && ed.y < ne) {
            int pos = atomicAdd(&cur[ed.y - ns], 1);
            csr[pos] = ed.x;
        }
    }
}

// ------- fused agg1 + gemm2: block owns 32 consecutive order-slots, HEAVY-FIRST. -------
// Phase A: H = relu(dinv^2*Z1[v] + sum w*Z1[s] + b1) -> LDS (XOR-swizzled 16B slots),
//   4-deep csr prefetch breaking the csr->row serial latency chain (R3 form, 43.6 us).
// Phase B: Z2'[v] = dinv[v] * (H @ W2), W2 staged in 4 x 8KB rounds (16KB LDS total).
__global__ void agg1_gemm2_kernel(const __bf16* __restrict__ Zs, const int* __restrict__ row_ptr,
                                  const int* __restrict__ counts, const int* __restrict__ csr,
                                  const float* __restrict__ dinv, const float* __restrict__ bias,
                                  const __bf16* __restrict__ PW, const int* __restrict__ order,
                                  __bf16* __restrict__ Z2, int n) {
    __shared__ __align__(16) __bf16 sH[32 * 128];  // 8 KB
    __shared__ bf16x8 sBp[512];                    // 8 KB (one k-chunk of packed W2)
    int t = threadIdx.x;  // 0..127
    const bf16x8* PW8 = (const bf16x8*)PW;

    int gbase = blockIdx.x * 32;
    int grp = t >> 4, c = t & 15;

    // hoist bias for this lane's 8 stored cols (true col j*16+c)
    float bs[8];
#pragma unroll
    for (int j = 0; j < 8; j++) bs[j] = bias[j * 16 + c];

    const bf16x8* Z8 = (const bf16x8*)Zs;
    for (int r = 0; r < 4; r++) {
        int lr = r * 8 + grp;           // local row 0..31
        int idx = gbase + lr;
        bf16x8 o = {};
        if (idx < n) {
            int v = order[(n - 1) - idx];   // heavy-first
            float dv = dinv[v];
            bf16x8 zc = Z8[(size_t)v * 16 + c];
            float sw = dv * dv;
            float acc[8];
#pragma unroll
            for (int j = 0; j < 8; j++) acc[j] = (float)zc[j] * sw;
            int start = row_ptr[v], cnt = counts[v];
            int i = 0;
            if (cnt >= 4) {
                int s0 = csr[start], s1 = csr[start + 1];
                int s2 = csr[start + 2], s3 = csr[start + 3];
                for (; i + 8 <= cnt; i += 4) {
                    int t0 = csr[start + i + 4], t1 = csr[start + i + 5];
                    int t2 = csr[start + i + 6], t3 = csr[start + i + 7];
                    bf16x8 m0 = Z8[(size_t)s0 * 16 + c];
                    bf16x8 m1 = Z8[(size_t)s1 * 16 + c];
                    bf16x8 m2 = Z8[(size_t)s2 * 16 + c];
                    bf16x8 m3 = Z8[(size_t)s3 * 16 + c];
                    float w0 = dinv[s0] * dv, w1 = dinv[s1] * dv;
                    float w2 = dinv[s2] * dv, w3 = dinv[s3] * dv;
#pragma unroll
                    for (int j = 0; j < 8; j++) acc[j] = fmaf(w0, (float)m0[j], acc[j]);
#pragma unroll
                    for (int j = 0; j < 8; j++) acc[j] = fmaf(w1, (float)m1[j], acc[j]);
#pragma unroll
                    for (int j = 0; j < 8; j++) acc[j] = fmaf(w2, (float)m2[j], acc[j]);
#pragma unroll
                    for (int j = 0; j < 8; j++) acc[j] = fmaf(w3, (float)m3[j], acc[j]);
                    s0 = t0; s1 = t1; s2 = t2; s3 = t3;
                }
                {   // drain the prefetched quad
                    bf16x8 m0 = Z8[(size_t)s0 * 16 + c];
                    bf16x8 m1 = Z8[(size_t)s1 * 16 + c];
                    bf16x8 m2 = Z8[(size_t)s2 * 16 + c];
                    bf16x8 m3 = Z8[(size_t)s3 * 16 + c];
                    float w0 = dinv[s0] * dv, w1 = dinv[s1] * dv;
                    float w2 = dinv[s2] * dv, w3 = dinv[s3] * dv;
#pragma unroll
                    for (int j = 0; j < 8; j++) acc[j] = fmaf(w0, (float)m0[j], acc[j]);
#pragma unroll
                    for (int j = 0; j < 8; j++) acc[j] = fmaf(w1, (float)m1[j], acc[j]);
#pragma unroll
                    for (int j = 0; j < 8; j++) acc[j] = fmaf(w2, (float)m2[j], acc[j]);
#pragma unroll
                    for (int j = 0; j < 8; j++) acc[j] = fmaf(w3, (float)m3[j], acc[j]);
                    i += 4;
                }
            }
            for (; i < cnt; i++) {
                int s0 = csr[start + i];
                float w0 = dinv[s0] * dv;
                bf16x8 m0 = Z8[(size_t)s0 * 16 + c];
#pragma unroll
                for (int j = 0; j < 8; j++) acc[j] = fmaf(w0, (float)m0[j], acc[j]);
            }
#pragma unroll
            for (int j = 0; j < 8; j++) o[j] = (__bf16)fmaxf(acc[j] + bs[j], 0.f);
        }
        // swizzled 16B-slot write: slot c -> c ^ (lr&7)
        *(bf16x8*)(sH + lr * 128 + ((c ^ (lr & 7)) << 3)) = o;
    }

    // ---- phase B: 4 rounds; each stages 8KB of W2 (k-chunk cc) then 8 MFMAs ----
    int wave = t >> 6, lane = t & 63;
    int qm = lane & 15, quad = lane >> 4;
    int lrow = wave * 16 + qm;

    f32x4 acc[8];
#pragma unroll
    for (int nt = 0; nt < 8; nt++) acc[nt] = (f32x4){0.f, 0.f, 0.f, 0.f};

#pragma unroll
    for (int cc = 0; cc < 4; cc++) {
        __syncthreads();  // round cc-1 reads done (and, at cc=0, all sH writes visible)
#pragma unroll
        for (int i = 0; i < 4; i++) {
            int idx = i * 128 + t;  // 0..511
            sBp[idx] = PW8[((idx >> 6) * 4 + cc) * 64 + (idx & 63)];
        }
        // A-fragment for this k-chunk from swizzled sH (overlaps with sBp stage)
        int slot = quad + cc * 4;  // 16B slot index within the 256B row
        bf16x8 a = *(const bf16x8*)(sH + lrow * 128 + ((slot ^ (lrow & 7)) << 3));
        __syncthreads();  // sBp visible
#pragma unroll
        for (int nt = 0; nt < 8; nt++) {
            bf16x8 bb = sBp[nt * 64 + lane];
            acc[nt] = __builtin_amdgcn_mfma_f32_16x16x32_bf16(a, bb, acc[nt], 0, 0, 0);
        }
    }

    // C/D: true col = nt*16+qm -> stored col qm*8+nt; local row = wave*16 + quad*4 + reg
#pragma unroll
    for (int reg = 0; reg < 4; reg++) {
        int lrr = wave * 16 + quad * 4 + reg;
        int gidx = gbase + lrr;
        if (gidx < n) {
            int v = order[(n - 1) - gidx];  // heavy-first (must match phase A mapping)
            float sc = dinv[v];  // prescale: Z2' = dinv[v] * Z2
            bf16x8 o;
#pragma unroll
            for (int nt = 0; nt < 8; nt++) o[nt] = (__bf16)(acc[nt][reg] * sc);
            *(bf16x8*)(Z2 + (size_t)v * D + qm * 8) = o;
        }
    }
}

// ------- agg2 + fc fused (heavy-first, Z2 PRESCALED by dinv): -------
// out[v] = relu(dinv_v * (sum_s Z2'[s] + Z2'[v]) + b2) @ Wfc + bfc
__global__ void agg2_fc_kernel(const __bf16* __restrict__ Zs, const int* __restrict__ row_ptr,
                               const int* __restrict__ counts, const int* __restrict__ csr,
                               const float* __restrict__ dinv, const float* __restrict__ bias,
                               const float* __restrict__ Wfc, const float* __restrict__ bfc,
                               const int* __restrict__ order, float* __restrict__ out, int n) {
    int t = blockIdx.x * 256 + threadIdx.x;
    int idx = t >> 4, c = t & 15;
    if (idx >= n) return;
    int v = order[(n - 1) - idx];   // heavy-first
    float dv = dinv[v];
    const bf16x8* Z8 = (const bf16x8*)Zs;
    bf16x8 zc = Z8[(size_t)v * 16 + c];  // self term: dinv_v^2 Z2[v] = dinv_v * Z2'[v]
    float acc[8];
#pragma unroll
    for (int j = 0; j < 8; j++) acc[j] = (float)zc[j];
    int start = row_ptr[v], cnt = counts[v];
    int i = 0;
    if (cnt >= 4) {
        int s0 = csr[start], s1 = csr[start + 1];
        int s2 = csr[start + 2], s3 = csr[start + 3];
        for (; i + 8 <= cnt; i += 4) {
            int t0 = csr[start + i + 4], t1 = csr[start + i + 5];
            int t2 = csr[start + i + 6], t3 = csr[start + i + 7];
            bf16x8 m0 = Z8[(size_t)s0 * 16 + c];
            bf16x8 m1 = Z8[(size_t)s1 * 16 + c];
            bf16x8 m2 = Z8[(size_t)s2 * 16 + c];
            bf16x8 m3 = Z8[(size_t)s3 * 16 + c];
#pragma unroll
            for (int j = 0; j < 8; j++) acc[j] += (float)m0[j];
#pragma unroll
            for (int j = 0; j < 8; j++) acc[j] += (float)m1[j];
#pragma unroll
            for (int j = 0; j < 8; j++) acc[j] += (float)m2[j];
#pragma unroll
            for (int j = 0; j < 8; j++) acc[j] += (float)m3[j];
            s0 = t0; s1 = t1; s2 = t2; s3 = t3;
        }
        {
            bf16x8 m0 = Z8[(size_t)s0 * 16 + c];
            bf16x8 m1 = Z8[(size_t)s1 * 16 + c];
            bf16x8 m2 = Z8[(size_t)s2 * 16 + c];
            bf16x8 m3 = Z8[(size_t)s3 * 16 + c];
#pragma unroll
            for (int j = 0; j < 8; j++) acc[j] += (float)m0[j];
#pragma unroll
            for (int j = 0; j < 8; j++) acc[j] += (float)m1[j];
#pragma unroll
            for (int j = 0; j < 8; j++) acc[j] += (float)m2[j];
#pragma unroll
            for (int j = 0; j < 8; j++) acc[j] += (float)m3[j];
            i += 4;
        }
    }
    for (; i < cnt; i++) {
        int s0 = csr[start + i];
        bf16x8 m0 = Z8[(size_t)s0 * 16 + c];
#pragma unroll
        for (int j = 0; j < 8; j++) acc[j] += (float)m0[j];
    }
    float a0 = 0.f, a1 = 0.f;
#pragma unroll
    for (int j = 0; j < 8; j++) {
        int p = j * 16 + c;  // true col
        float hj = fmaxf(fmaf(dv, acc[j], bias[p]), 0.f);
        a0 = fmaf(hj, Wfc[p * 2], a0);
        a1 = fmaf(hj, Wfc[p * 2 + 1], a1);
    }
#pragma unroll
    for (int off = 8; off > 0; off >>= 1) {
        a0 += __shfl_down(a0, off, 16);
        a1 += __shfl_down(a1, off, 16);
    }
    if (c == 0) {
        out[(size_t)v * 2 + 0] = a0 + bfc[0];
        out[(size_t)v * 2 + 1] = a1 + bfc[1];
    }
}

// ---------------- launch ----------------

extern "C" void kernel_launch(void* const* d_in, const int* in_sizes, int n_in,
                              void* d_out, int out_size, void* d_ws, size_t ws_size,
                              hipStream_t stream) {
    const float* x   = (const float*)d_in[0];
    const int*   ei  = (const int*)d_in[1];
    const float* W1  = (const float*)d_in[2];
    const float* b1  = (const float*)d_in[3];
    const float* W2  = (const float*)d_in[4];
    const float* b2  = (const float*)d_in[5];
    const float* Wfc = (const float*)d_in[6];
    const float* bfc = (const float*)d_in[7];
    float* out = (float*)d_out;

    int n = in_sizes[0] / D;   // 100000
    int e = in_sizes[1] / 2;   // 640000
    const int* src = ei;
    const int* dst = ei + e;

    int bucketW = (n + NBUCKET - 1) / NBUCKET;   // 1563
    int subW = (bucketW + 3) / 4;                // 391 (fits bins[400])

    // workspace layout (16B-aligned at these sizes)
    char* ws = (char*)d_ws;
    size_t nb = (size_t)n * 4;
    int*    counts  = (int*)(ws);
    float*  dinv    = (float*)(ws + nb);
    int*    rowptr  = (int*)(ws + 2 * nb);
    int*    partial = (int*)(ws + 3 * nb);                    // 1024 B
    int*    bcur    = (int*)(ws + 3 * nb + 1024);             // 256 B
    int*    deghist = (int*)(ws + 3 * nb + 1280);             // 256 B
    int*    degcur  = (int*)(ws + 3 * nb + 1536);             // 256 B (+256 pad)
    int*    order   = (int*)(ws + 3 * nb + 2048);             // n*4
    int2*   bedges  = (int2*)(ws + 4 * nb + 2048);            // 8 MB
    size_t  off1    = 4 * nb + 2048 + (size_t)NBUCKET * BCAP * 8;
    int*    csr     = (int*)(ws + off1);                      // e*4
    __bf16* pw      = (__bf16*)(ws + off1 + (size_t)e * 4);   // 64 KB packed (W1|W2)
    __bf16* z1      = (__bf16*)(ws + off1 + (size_t)e * 4 + 65536);
    __bf16* z2      = z1 + (size_t)n * D;

    int eab = ((e + 3) / 4 + 255) / 256;       // bucketize blocks (625)
    int gb  = (n + 63) / 64;                   // gemm blocks (1563)
    int gb2 = (n + 31) / 32;                   // fused agg1+gemm2 blocks (3125)
    int ab  = ((n * 16) + 255) / 256;          // agg blocks (6250)

    prep_kernel<<<129, 256, 0, stream>>>(W1, W2, pw, bcur, deghist, degcur);
    mega1_kernel<<<gb + eab, 256, 0, stream>>>(x, pw, z1, n, gb, src, dst,
                                               bcur, bedges, e, bucketW);
    count2_kernel<<<256, 256, 0, stream>>>(bedges, bcur, counts, dinv, partial, deghist,
                                           n, bucketW, subW);
    scanfill_kernel<<<256, 256, 0, stream>>>(bedges, bcur, counts, partial, deghist,
                                             rowptr, csr, degcur, order, n, bucketW, subW);
    agg1_gemm2_kernel<<<gb2, 128, 0, stream>>>(z1, rowptr, counts, csr, dinv, b1,
                                               pw + 16384, order, z2, n);
    agg2_fc_kernel<<<ab, 256, 0, stream>>>(z2, rowptr, counts, csr, dinv, b2, Wfc, bfc,
                                           order, out, n);
}

// Round 11
// 216.259 us; speedup vs baseline: 1.0838x; 1.0797x over previous
//
#include <hip/hip_runtime.h>
#include <hip/hip_bf16.h>

#define D 128
#define NBUCKET 64
#define BCAP 16384   // per-bucket edge capacity (mean 10k -> huge margin)

typedef __bf16 bf16x8 __attribute__((ext_vector_type(8)));
typedef float f32x4 __attribute__((ext_vector_type(4)));

// stored col j  <->  true col PI(j) = (j&7)*16 + (j>>3);  PI_inv(c) = (c&15)*8 + (c>>4)

// -------- prep: pack weights + zero bucket cursors + degree hist + degree cursors --------
__global__ void prep_kernel(const float* __restrict__ W1, const float* __restrict__ W2,
                            __bf16* __restrict__ pw, int* __restrict__ bucket_cursor,
                            int* __restrict__ deghist, int* __restrict__ degcur) {
    int b = blockIdx.x;
    if (b < 128) {
        int t = b * 256 + threadIdx.x;  // 0..32767
        int which = t >> 14, idx = t & 16383;
        const float* W = which ? W2 : W1;
        float w = W[idx];
        int k = idx >> 7, nn = idx & 127;
        int ks = which ? (((k & 15) << 3) | (k >> 4)) : k;  // PI_inv for layer 2
        int ntile = nn >> 4, nl = nn & 15;
        int kchunk = ks >> 5, quad = (ks >> 3) & 3, j = ks & 7;
        int o = (((ntile * 4 + kchunk) * 64 + quad * 16 + nl) << 3) + j;
        pw[(size_t)which * 16384 + o] = (__bf16)w;
    } else {
        int t = threadIdx.x;
        if (t < NBUCKET) bucket_cursor[t] = 0;
        else if (t < 128) deghist[t - 64] = 0;
        else if (t < 192) degcur[t - 128] = 0;   // degcur starts at 0 (within-bin cursor)
    }
}

// ------- mega1: gemm1 (blocks [0,gb)) + edge bucketize (blocks [gb, gb+eab)) -------
// gemm1: Zs = X(fp32) @ W1bf16, A split 2-term, B staged in LDS (proven R10 form).
__global__ void mega1_kernel(const float* __restrict__ X, const __bf16* __restrict__ PW,
                             __bf16* __restrict__ Zs, int nrows, int gb,
                             const int* __restrict__ src, const int* __restrict__ dst,
                             int* __restrict__ bucket_cursor, int2* __restrict__ bucket_edges,
                             int e, int bucketW) {
    __shared__ __align__(16) char smem[32768];
    int t = threadIdx.x;
    int b = blockIdx.x;
    if (b >= gb) {
        // ---- bucketize path ----
        int* hist = (int*)smem;          // 64
        int* gbase = hist + 64;          // 64
        if (t < NBUCKET) hist[t] = 0;
        __syncthreads();
        int i0 = ((b - gb) * 256 + t) * 4;
        int sv[4], dv[4], bk[4], ls[4];
        int nv = 0;
        if (i0 + 4 <= e) {
            int4 s4 = *(const int4*)(src + i0);
            int4 d4 = *(const int4*)(dst + i0);
            sv[0] = s4.x; sv[1] = s4.y; sv[2] = s4.z; sv[3] = s4.w;
            dv[0] = d4.x; dv[1] = d4.y; dv[2] = d4.z; dv[3] = d4.w;
            nv = 4;
        } else {
            for (int i = i0; i < e; i++) { sv[nv] = src[i]; dv[nv] = dst[i]; nv++; }
        }
        for (int u = 0; u < nv; u++) {
            bk[u] = dv[u] / bucketW;
            ls[u] = atomicAdd(&hist[bk[u]], 1);
        }
        __syncthreads();
        if (t < NBUCKET) gbase[t] = atomicAdd(&bucket_cursor[t], hist[t]);
        __syncthreads();
        for (int u = 0; u < nv; u++) {
            int pos = bk[u] * BCAP + gbase[bk[u]] + ls[u];
            bucket_edges[pos] = make_int2(sv[u], dv[u]);
        }
        return;
    }
    // ---- gemm1 path ----
    bf16x8* sB = (bf16x8*)smem;  // 32 KB packed W
    const bf16x8* PW8 = (const bf16x8*)PW;
#pragma unroll
    for (int i = 0; i < 8; i++) sB[t + 256 * i] = PW8[t + 256 * i];

    int wave = t >> 6, lane = t & 63;
    int qm = lane & 15, quad = lane >> 4;
    int r0 = b * 64 + wave * 16;
    int row = r0 + qm;
    bool valid = row < nrows;
    const float* xr = X + (size_t)row * D + quad * 8;

    bf16x8 ahi[4], alo[4];
#pragma unroll
    for (int c = 0; c < 4; c++) {
        float4 zf = {0.f, 0.f, 0.f, 0.f};
        float4 xa = valid ? ((const float4*)(xr + c * 32))[0] : zf;
        float4 xb = valid ? ((const float4*)(xr + c * 32))[1] : zf;
        float xs[8] = {xa.x, xa.y, xa.z, xa.w, xb.x, xb.y, xb.z, xb.w};
        bf16x8 h, l;
#pragma unroll
        for (int j = 0; j < 8; j++) {
            float v = xs[j];
            __bf16 hh = (__bf16)v;
            h[j] = hh;
            l[j] = (__bf16)(v - (float)hh);
        }
        ahi[c] = h; alo[c] = l;
    }

    f32x4 acc[8];
#pragma unroll
    for (int nt = 0; nt < 8; nt++) acc[nt] = (f32x4){0.f, 0.f, 0.f, 0.f};

    __syncthreads();

#pragma unroll
    for (int c = 0; c < 4; c++) {
#pragma unroll
        for (int nt = 0; nt < 8; nt++) {
            bf16x8 bb = sB[(nt * 4 + c) * 64 + lane];
            acc[nt] = __builtin_amdgcn_mfma_f32_16x16x32_bf16(ahi[c], bb, acc[nt], 0, 0, 0);
            acc[nt] = __builtin_amdgcn_mfma_f32_16x16x32_bf16(alo[c], bb, acc[nt], 0, 0, 0);
        }
    }

    // C/D: true col = nt*16+qm -> stored col qm*8+nt; row = quad*4+reg
#pragma unroll
    for (int reg = 0; reg < 4; reg++) {
        int orow = r0 + quad * 4 + reg;
        if (orow < nrows) {
            bf16x8 o;
#pragma unroll
            for (int nt = 0; nt < 8; nt++) o[nt] = (__bf16)acc[nt][reg];
            *(bf16x8*)(Zs + (size_t)orow * D + qm * 8) = o;
        }
    }
}

// ------- countb (R9): ONE block per bucket, 1024 threads. Each edge read is useful -------
// (bucket == node range, no filter). Removes the old 4x bedges read amplification.
__global__ void countb_kernel(const int2* __restrict__ bucket_edges,
                              const int* __restrict__ bucket_cursor,
                              int* __restrict__ counts, float* __restrict__ dinv,
                              int* __restrict__ partial, int* __restrict__ deghist,
                              int n, int bucketW) {
    __shared__ int bins[1568];
    __shared__ int sm[1024];
    __shared__ int hb[64];
    int bk = blockIdx.x, t = threadIdx.x;
    int ns = bk * bucketW;
    int ne = min(ns + bucketW, n);
    int w = ne - ns;
    if (w <= 0) { if (t == 0) partial[bk] = 0; return; }
    for (int i = t; i < w; i += 1024) bins[i] = 0;
    if (t < 64) hb[t] = 0;
    __syncthreads();
    int m = bucket_cursor[bk];
    const int2* eb = bucket_edges + (size_t)bk * BCAP;
    for (int i = t; i < m; i += 1024) {
        atomicAdd(&bins[eb[i].y - ns], 1);
    }
    __syncthreads();
    int s = 0;
    for (int i = t; i < w; i += 1024) {
        int c = bins[i];
        counts[ns + i] = c;
        dinv[ns + i] = rsqrtf((float)(c + 1));  // +1 self loop
        atomicAdd(&hb[min(c, 63)], 1);
        s += c;
    }
    sm[t] = s; __syncthreads();
    for (int off = 512; off > 0; off >>= 1) { if (t < off) sm[t] += sm[t + off]; __syncthreads(); }
    if (t == 0) partial[bk] = sm[0];
    if (t < 64 && hb[t]) atomicAdd(&deghist[t], hb[t]);
}

// ------- fillb (R9): ONE block per bucket, 1024 threads. Inline exclusive scans of -------
// partial[64] / deghist[64]; local counts scan -> row_ptr; CSR scatter (1x edge read);
// degree-sorted order scatter: order idx = dgex[bin] + degcur-base + local rank.
__global__ void fillb_kernel(const int2* __restrict__ bucket_edges,
                             const int* __restrict__ bucket_cursor,
                             const int* __restrict__ counts,
                             const int* __restrict__ partial,
                             const int* __restrict__ deghist,
                             int* __restrict__ row_ptr, int* __restrict__ csr,
                             int* __restrict__ degcur, int* __restrict__ order,
                             int n, int bucketW) {
    __shared__ int cur[1568];
    __shared__ int sm[1024];
    __shared__ int hb2[64];
    __shared__ int gb2[64];
    __shared__ int dgex[64];
    __shared__ int pexs;
    int bk = blockIdx.x, t = threadIdx.x;
    int ns = bk * bucketW;
    int ne = min(ns + bucketW, n);
    int w = ne - ns;
    if (w <= 0) return;
    // ---- inline exclusive scan of partial[64]; capture this bucket's base ----
    int pv = (t < 64) ? partial[t] : 0;
    sm[t] = pv; __syncthreads();
    for (int off = 1; off < 64; off <<= 1) {
        int u = (t >= off && t < 64) ? sm[t - off] : 0;
        __syncthreads();
        if (t < 64) sm[t] += u;
        __syncthreads();
    }
    if (t == bk) pexs = sm[t] - pv;
    __syncthreads();
    int pbase = pexs;
    // ---- inline exclusive scan of deghist[64] ----
    int dh = (t < 64) ? deghist[t] : 0;
    sm[t] = dh; __syncthreads();
    for (int off = 1; off < 64; off <<= 1) {
        int u = (t >= off && t < 64) ? sm[t - off] : 0;
        __syncthreads();
        if (t < 64) sm[t] += u;
        __syncthreads();
    }
    if (t < 64) { dgex[t] = sm[t] - dh; hb2[t] = 0; }
    __syncthreads();
    // ---- counts scan (pairs; 1024 threads cover 2048 >= w) ----
    int i0 = t * 2;
    int c0 = (i0 < w) ? counts[ns + i0] : 0;
    int c1 = (i0 + 1 < w) ? counts[ns + i0 + 1] : 0;
    sm[t] = c0 + c1; __syncthreads();
    int own = c0 + c1;
    for (int off = 1; off < 1024; off <<= 1) {
        int u = (t >= off) ? sm[t - off] : 0;
        __syncthreads();
        sm[t] += u;
        __syncthreads();
    }
    int base = pbase + sm[t] - own;
    if (i0 < w)     { row_ptr[ns + i0] = base;          cur[i0] = base; }
    if (i0 + 1 < w) { row_ptr[ns + i0 + 1] = base + c0; cur[i0 + 1] = base + c0; }
    // degree-order: local ranks within block per bin
    int bin0 = min(c0, 63), bin1 = min(c1, 63);
    int r0 = (i0 < w) ? atomicAdd(&hb2[bin0], 1) : 0;
    int r1 = (i0 + 1 < w) ? atomicAdd(&hb2[bin1], 1) : 0;
    __syncthreads();
    if (t < 64 && hb2[t]) gb2[t] = atomicAdd(&degcur[t], hb2[t]);
    __syncthreads();
    if (i0 < w)     order[dgex[bin0] + gb2[bin0] + r0] = ns + i0;
    if (i0 + 1 < w) order[dgex[bin1] + gb2[bin1] + r1] = ns + i0 + 1;
    __syncthreads();
    int m = bucket_cursor[bk];
    const int2* eb = bucket_edges + (size_t)bk * BCAP;
    for (int i = t; i < m; i += 1024) {
        int2 ed = eb[i];
        int pos = atomicAdd(&cur[ed.y - ns], 1);
        csr[pos] = ed.x;
    }
}

// ------- fused agg1 + gemm2: block owns 32 consecutive order-slots, HEAVY-FIRST. -------
// Phase A: H = relu(dinv^2*Z1[v] + sum w*Z1[s] + b1) -> LDS (XOR-swizzled 16B slots),
//   4-deep csr prefetch breaking the csr->row serial latency chain (R3 form, 43.6 us).
// Phase B: Z2'[v] = dinv[v] * (H @ W2), W2 staged in 4 x 8KB rounds (16KB LDS total).
__global__ void agg1_gemm2_kernel(const __bf16* __restrict__ Zs, const int* __restrict__ row_ptr,
                                  const int* __restrict__ counts, const int* __restrict__ csr,
                                  const float* __restrict__ dinv, const float* __restrict__ bias,
                                  const __bf16* __restrict__ PW, const int* __restrict__ order,
                                  __bf16* __restrict__ Z2, int n) {
    __shared__ __align__(16) __bf16 sH[32 * 128];  // 8 KB
    __shared__ bf16x8 sBp[512];                    // 8 KB (one k-chunk of packed W2)
    int t = threadIdx.x;  // 0..127
    const bf16x8* PW8 = (const bf16x8*)PW;

    int gbase = blockIdx.x * 32;
    int grp = t >> 4, c = t & 15;

    // hoist bias for this lane's 8 stored cols (true col j*16+c)
    float bs[8];
#pragma unroll
    for (int j = 0; j < 8; j++) bs[j] = bias[j * 16 + c];

    const bf16x8* Z8 = (const bf16x8*)Zs;
    for (int r = 0; r < 4; r++) {
        int lr = r * 8 + grp;           // local row 0..31
        int idx = gbase + lr;
        bf16x8 o = {};
        if (idx < n) {
            int v = order[(n - 1) - idx];   // heavy-first
            float dv = dinv[v];
            bf16x8 zc = Z8[(size_t)v * 16 + c];
            float sw = dv * dv;
            float acc[8];
#pragma unroll
            for (int j = 0; j < 8; j++) acc[j] = (float)zc[j] * sw;
            int start = row_ptr[v], cnt = counts[v];
            int i = 0;
            if (cnt >= 4) {
                int s0 = csr[start], s1 = csr[start + 1];
                int s2 = csr[start + 2], s3 = csr[start + 3];
                for (; i + 8 <= cnt; i += 4) {
                    int t0 = csr[start + i + 4], t1 = csr[start + i + 5];
                    int t2 = csr[start + i + 6], t3 = csr[start + i + 7];
                    bf16x8 m0 = Z8[(size_t)s0 * 16 + c];
                    bf16x8 m1 = Z8[(size_t)s1 * 16 + c];
                    bf16x8 m2 = Z8[(size_t)s2 * 16 + c];
                    bf16x8 m3 = Z8[(size_t)s3 * 16 + c];
                    float w0 = dinv[s0] * dv, w1 = dinv[s1] * dv;
                    float w2 = dinv[s2] * dv, w3 = dinv[s3] * dv;
#pragma unroll
                    for (int j = 0; j < 8; j++) acc[j] = fmaf(w0, (float)m0[j], acc[j]);
#pragma unroll
                    for (int j = 0; j < 8; j++) acc[j] = fmaf(w1, (float)m1[j], acc[j]);
#pragma unroll
                    for (int j = 0; j < 8; j++) acc[j] = fmaf(w2, (float)m2[j], acc[j]);
#pragma unroll
                    for (int j = 0; j < 8; j++) acc[j] = fmaf(w3, (float)m3[j], acc[j]);
                    s0 = t0; s1 = t1; s2 = t2; s3 = t3;
                }
                {   // drain the prefetched quad
                    bf16x8 m0 = Z8[(size_t)s0 * 16 + c];
                    bf16x8 m1 = Z8[(size_t)s1 * 16 + c];
                    bf16x8 m2 = Z8[(size_t)s2 * 16 + c];
                    bf16x8 m3 = Z8[(size_t)s3 * 16 + c];
                    float w0 = dinv[s0] * dv, w1 = dinv[s1] * dv;
                    float w2 = dinv[s2] * dv, w3 = dinv[s3] * dv;
#pragma unroll
                    for (int j = 0; j < 8; j++) acc[j] = fmaf(w0, (float)m0[j], acc[j]);
#pragma unroll
                    for (int j = 0; j < 8; j++) acc[j] = fmaf(w1, (float)m1[j], acc[j]);
#pragma unroll
                    for (int j = 0; j < 8; j++) acc[j] = fmaf(w2, (float)m2[j], acc[j]);
#pragma unroll
                    for (int j = 0; j < 8; j++) acc[j] = fmaf(w3, (float)m3[j], acc[j]);
                    i += 4;
                }
            }
            for (; i < cnt; i++) {
                int s0 = csr[start + i];
                float w0 = dinv[s0] * dv;
                bf16x8 m0 = Z8[(size_t)s0 * 16 + c];
#pragma unroll
                for (int j = 0; j < 8; j++) acc[j] = fmaf(w0, (float)m0[j], acc[j]);
            }
#pragma unroll
            for (int j = 0; j < 8; j++) o[j] = (__bf16)fmaxf(acc[j] + bs[j], 0.f);
        }
        // swizzled 16B-slot write: slot c -> c ^ (lr&7)
        *(bf16x8*)(sH + lr * 128 + ((c ^ (lr & 7)) << 3)) = o;
    }

    // ---- phase B: 4 rounds; each stages 8KB of W2 (k-chunk cc) then 8 MFMAs ----
    int wave = t >> 6, lane = t & 63;
    int qm = lane & 15, quad = lane >> 4;
    int lrow = wave * 16 + qm;

    f32x4 acc[8];
#pragma unroll
    for (int nt = 0; nt < 8; nt++) acc[nt] = (f32x4){0.f, 0.f, 0.f, 0.f};

#pragma unroll
    for (int cc = 0; cc < 4; cc++) {
        __syncthreads();  // round cc-1 reads done (and, at cc=0, all sH writes visible)
#pragma unroll
        for (int i = 0; i < 4; i++) {
            int idx = i * 128 + t;  // 0..511
            sBp[idx] = PW8[((idx >> 6) * 4 + cc) * 64 + (idx & 63)];
        }
        // A-fragment for this k-chunk from swizzled sH (overlaps with sBp stage)
        int slot = quad + cc * 4;  // 16B slot index within the 256B row
        bf16x8 a = *(const bf16x8*)(sH + lrow * 128 + ((slot ^ (lrow & 7)) << 3));
        __syncthreads();  // sBp visible
#pragma unroll
        for (int nt = 0; nt < 8; nt++) {
            bf16x8 bb = sBp[nt * 64 + lane];
            acc[nt] = __builtin_amdgcn_mfma_f32_16x16x32_bf16(a, bb, acc[nt], 0, 0, 0);
        }
    }

    // C/D: true col = nt*16+qm -> stored col qm*8+nt; local row = wave*16 + quad*4 + reg
#pragma unroll
    for (int reg = 0; reg < 4; reg++) {
        int lrr = wave * 16 + quad * 4 + reg;
        int gidx = gbase + lrr;
        if (gidx < n) {
            int v = order[(n - 1) - gidx];  // heavy-first (must match phase A mapping)
            float sc = dinv[v];  // prescale: Z2' = dinv[v] * Z2
            bf16x8 o;
#pragma unroll
            for (int nt = 0; nt < 8; nt++) o[nt] = (__bf16)(acc[nt][reg] * sc);
            *(bf16x8*)(Z2 + (size_t)v * D + qm * 8) = o;
        }
    }
}

// ------- agg2 + fc fused (heavy-first, Z2 PRESCALED by dinv): -------
// out[v] = relu(dinv_v * (sum_s Z2'[s] + Z2'[v]) + b2) @ Wfc + bfc
__global__ void agg2_fc_kernel(const __bf16* __restrict__ Zs, const int* __restrict__ row_ptr,
                               const int* __restrict__ counts, const int* __restrict__ csr,
                               const float* __restrict__ dinv, const float* __restrict__ bias,
                               const float* __restrict__ Wfc, const float* __restrict__ bfc,
                               const int* __restrict__ order, float* __restrict__ out, int n) {
    int t = blockIdx.x * 256 + threadIdx.x;
    int idx = t >> 4, c = t & 15;
    if (idx >= n) return;
    int v = order[(n - 1) - idx];   // heavy-first
    float dv = dinv[v];
    const bf16x8* Z8 = (const bf16x8*)Zs;
    bf16x8 zc = Z8[(size_t)v * 16 + c];  // self term: dinv_v^2 Z2[v] = dinv_v * Z2'[v]
    float acc[8];
#pragma unroll
    for (int j = 0; j < 8; j++) acc[j] = (float)zc[j];
    int start = row_ptr[v], cnt = counts[v];
    int i = 0;
    if (cnt >= 4) {
        int s0 = csr[start], s1 = csr[start + 1];
        int s2 = csr[start + 2], s3 = csr[start + 3];
        for (; i + 8 <= cnt; i += 4) {
            int t0 = csr[start + i + 4], t1 = csr[start + i + 5];
            int t2 = csr[start + i + 6], t3 = csr[start + i + 7];
            bf16x8 m0 = Z8[(size_t)s0 * 16 + c];
            bf16x8 m1 = Z8[(size_t)s1 * 16 + c];
            bf16x8 m2 = Z8[(size_t)s2 * 16 + c];
            bf16x8 m3 = Z8[(size_t)s3 * 16 + c];
#pragma unroll
            for (int j = 0; j < 8; j++) acc[j] += (float)m0[j];
#pragma unroll
            for (int j = 0; j < 8; j++) acc[j] += (float)m1[j];
#pragma unroll
            for (int j = 0; j < 8; j++) acc[j] += (float)m2[j];
#pragma unroll
            for (int j = 0; j < 8; j++) acc[j] += (float)m3[j];
            s0 = t0; s1 = t1; s2 = t2; s3 = t3;
        }
        {
            bf16x8 m0 = Z8[(size_t)s0 * 16 + c];
            bf16x8 m1 = Z8[(size_t)s1 * 16 + c];
            bf16x8 m2 = Z8[(size_t)s2 * 16 + c];
            bf16x8 m3 = Z8[(size_t)s3 * 16 + c];
#pragma unroll
            for (int j = 0; j < 8; j++) acc[j] += (float)m0[j];
#pragma unroll
            for (int j = 0; j < 8; j++) acc[j] += (float)m1[j];
#pragma unroll
            for (int j = 0; j < 8; j++) acc[j] += (float)m2[j];
#pragma unroll
            for (int j = 0; j < 8; j++) acc[j] += (float)m3[j];
            i += 4;
        }
    }
    for (; i < cnt; i++) {
        int s0 = csr[start + i];
        bf16x8 m0 = Z8[(size_t)s0 * 16 + c];
#pragma unroll
        for (int j = 0; j < 8; j++) acc[j] += (float)m0[j];
    }
    float a0 = 0.f, a1 = 0.f;
#pragma unroll
    for (int j = 0; j < 8; j++) {
        int p = j * 16 + c;  // true col
        float hj = fmaxf(fmaf(dv, acc[j], bias[p]), 0.f);
        a0 = fmaf(hj, Wfc[p * 2], a0);
        a1 = fmaf(hj, Wfc[p * 2 + 1], a1);
    }
#pragma unroll
    for (int off = 8; off > 0; off >>= 1) {
        a0 += __shfl_down(a0, off, 16);
        a1 += __shfl_down(a1, off, 16);
    }
    if (c == 0) {
        out[(size_t)v * 2 + 0] = a0 + bfc[0];
        out[(size_t)v * 2 + 1] = a1 + bfc[1];
    }
}

// ---------------- launch ----------------

extern "C" void kernel_launch(void* const* d_in, const int* in_sizes, int n_in,
                              void* d_out, int out_size, void* d_ws, size_t ws_size,
                              hipStream_t stream) {
    const float* x   = (const float*)d_in[0];
    const int*   ei  = (const int*)d_in[1];
    const float* W1  = (const float*)d_in[2];
    const float* b1  = (const float*)d_in[3];
    const float* W2  = (const float*)d_in[4];
    const float* b2  = (const float*)d_in[5];
    const float* Wfc = (const float*)d_in[6];
    const float* bfc = (const float*)d_in[7];
    float* out = (float*)d_out;

    int n = in_sizes[0] / D;   // 100000
    int e = in_sizes[1] / 2;   // 640000
    const int* src = ei;
    const int* dst = ei + e;

    int bucketW = (n + NBUCKET - 1) / NBUCKET;   // 1563 (<= 1568 LDS bins)

    // workspace layout (16B-aligned at these sizes)
    char* ws = (char*)d_ws;
    size_t nb = (size_t)n * 4;
    int*    counts  = (int*)(ws);
    float*  dinv    = (float*)(ws + nb);
    int*    rowptr  = (int*)(ws + 2 * nb);
    int*    partial = (int*)(ws + 3 * nb);                    // 1024 B (64 used)
    int*    bcur    = (int*)(ws + 3 * nb + 1024);             // 256 B
    int*    deghist = (int*)(ws + 3 * nb + 1280);             // 256 B
    int*    degcur  = (int*)(ws + 3 * nb + 1536);             // 256 B (+256 pad)
    int*    order   = (int*)(ws + 3 * nb + 2048);             // n*4
    int2*   bedges  = (int2*)(ws + 4 * nb + 2048);            // 8 MB
    size_t  off1    = 4 * nb + 2048 + (size_t)NBUCKET * BCAP * 8;
    int*    csr     = (int*)(ws + off1);                      // e*4
    __bf16* pw      = (__bf16*)(ws + off1 + (size_t)e * 4);   // 64 KB packed (W1|W2)
    __bf16* z1      = (__bf16*)(ws + off1 + (size_t)e * 4 + 65536);
    __bf16* z2      = z1 + (size_t)n * D;

    int eab = ((e + 3) / 4 + 255) / 256;       // bucketize blocks (625)
    int gb  = (n + 63) / 64;                   // gemm blocks (1563)
    int gb2 = (n + 31) / 32;                   // fused agg1+gemm2 blocks (3125)
    int ab  = ((n * 16) + 255) / 256;          // agg blocks (6250)

    prep_kernel<<<129, 256, 0, stream>>>(W1, W2, pw, bcur, deghist, degcur);
    mega1_kernel<<<gb + eab, 256, 0, stream>>>(x, pw, z1, n, gb, src, dst,
                                               bcur, bedges, e, bucketW);
    countb_kernel<<<NBUCKET, 1024, 0, stream>>>(bedges, bcur, counts, dinv, partial,
                                                deghist, n, bucketW);
    fillb_kernel<<<NBUCKET, 1024, 0, stream>>>(bedges, bcur, counts, partial, deghist,
                                               rowptr, csr, degcur, order, n, bucketW);
    agg1_gemm2_kernel<<<gb2, 128, 0, stream>>>(z1, rowptr, counts, csr, dinv, b1,
                                               pw + 16384, order, z2, n);
    agg2_fc_kernel<<<ab, 256, 0, stream>>>(z2, rowptr, counts, csr, dinv, b2, Wfc, bfc,
                                           order, out, n);
}

// Round 12
// 211.117 us; speedup vs baseline: 1.1102x; 1.0244x over previous
//
#include <hip/hip_runtime.h>
#include <hip/hip_bf16.h>

#define D 128
#define NBUCKET 64
#define BCAP 16384      // per-bucket edge capacity (mean 10k -> huge margin)
#define CSRCAP 12288    // LDS csr-segment capacity (mean 10k, sigma ~99 -> 23-sigma margin)

typedef __bf16 bf16x8 __attribute__((ext_vector_type(8)));
typedef float f32x4 __attribute__((ext_vector_type(4)));

// stored col j  <->  true col PI(j) = (j&7)*16 + (j>>3);  PI_inv(c) = (c&15)*8 + (c>>4)

// -------- prep: pack weights + zero bucket cursors + degree hist + degree cursors --------
__global__ void prep_kernel(const float* __restrict__ W1, const float* __restrict__ W2,
                            __bf16* __restrict__ pw, int* __restrict__ bucket_cursor,
                            int* __restrict__ deghist, int* __restrict__ degcur) {
    int b = blockIdx.x;
    if (b < 128) {
        int t = b * 256 + threadIdx.x;  // 0..32767
        int which = t >> 14, idx = t & 16383;
        const float* W = which ? W2 : W1;
        float w = W[idx];
        int k = idx >> 7, nn = idx & 127;
        int ks = which ? (((k & 15) << 3) | (k >> 4)) : k;  // PI_inv for layer 2
        int ntile = nn >> 4, nl = nn & 15;
        int kchunk = ks >> 5, quad = (ks >> 3) & 3, j = ks & 7;
        int o = (((ntile * 4 + kchunk) * 64 + quad * 16 + nl) << 3) + j;
        pw[(size_t)which * 16384 + o] = (__bf16)w;
    } else {
        int t = threadIdx.x;
        if (t < NBUCKET) bucket_cursor[t] = 0;
        else if (t < 128) deghist[t - 64] = 0;
        else if (t < 192) degcur[t - 128] = 0;   // degcur starts at 0 (within-bin cursor)
    }
}

// ------- mega1: gemm1 (blocks [0,gb)) + edge bucketize (blocks [gb, gb+eab)) -------
// gemm1: Zs = X(fp32) @ W1bf16, A split 2-term, B staged in LDS (proven R10 form).
__global__ void mega1_kernel(const float* __restrict__ X, const __bf16* __restrict__ PW,
                             __bf16* __restrict__ Zs, int nrows, int gb,
                             const int* __restrict__ src, const int* __restrict__ dst,
                             int* __restrict__ bucket_cursor, int2* __restrict__ bucket_edges,
                             int e, int bucketW) {
    __shared__ __align__(16) char smem[32768];
    int t = threadIdx.x;
    int b = blockIdx.x;
    if (b >= gb) {
        // ---- bucketize path ----
        int* hist = (int*)smem;          // 64
        int* gbase = hist + 64;          // 64
        if (t < NBUCKET) hist[t] = 0;
        __syncthreads();
        int i0 = ((b - gb) * 256 + t) * 4;
        int sv[4], dv[4], bk[4], ls[4];
        int nv = 0;
        if (i0 + 4 <= e) {
            int4 s4 = *(const int4*)(src + i0);
            int4 d4 = *(const int4*)(dst + i0);
            sv[0] = s4.x; sv[1] = s4.y; sv[2] = s4.z; sv[3] = s4.w;
            dv[0] = d4.x; dv[1] = d4.y; dv[2] = d4.z; dv[3] = d4.w;
            nv = 4;
        } else {
            for (int i = i0; i < e; i++) { sv[nv] = src[i]; dv[nv] = dst[i]; nv++; }
        }
        for (int u = 0; u < nv; u++) {
            bk[u] = dv[u] / bucketW;
            ls[u] = atomicAdd(&hist[bk[u]], 1);
        }
        __syncthreads();
        if (t < NBUCKET) gbase[t] = atomicAdd(&bucket_cursor[t], hist[t]);
        __syncthreads();
        for (int u = 0; u < nv; u++) {
            int pos = bk[u] * BCAP + gbase[bk[u]] + ls[u];
            bucket_edges[pos] = make_int2(sv[u], dv[u]);
        }
        return;
    }
    // ---- gemm1 path ----
    bf16x8* sB = (bf16x8*)smem;  // 32 KB packed W
    const bf16x8* PW8 = (const bf16x8*)PW;
#pragma unroll
    for (int i = 0; i < 8; i++) sB[t + 256 * i] = PW8[t + 256 * i];

    int wave = t >> 6, lane = t & 63;
    int qm = lane & 15, quad = lane >> 4;
    int r0 = b * 64 + wave * 16;
    int row = r0 + qm;
    bool valid = row < nrows;
    const float* xr = X + (size_t)row * D + quad * 8;

    bf16x8 ahi[4], alo[4];
#pragma unroll
    for (int c = 0; c < 4; c++) {
        float4 zf = {0.f, 0.f, 0.f, 0.f};
        float4 xa = valid ? ((const float4*)(xr + c * 32))[0] : zf;
        float4 xb = valid ? ((const float4*)(xr + c * 32))[1] : zf;
        float xs[8] = {xa.x, xa.y, xa.z, xa.w, xb.x, xb.y, xb.z, xb.w};
        bf16x8 h, l;
#pragma unroll
        for (int j = 0; j < 8; j++) {
            float v = xs[j];
            __bf16 hh = (__bf16)v;
            h[j] = hh;
            l[j] = (__bf16)(v - (float)hh);
        }
        ahi[c] = h; alo[c] = l;
    }

    f32x4 acc[8];
#pragma unroll
    for (int nt = 0; nt < 8; nt++) acc[nt] = (f32x4){0.f, 0.f, 0.f, 0.f};

    __syncthreads();

#pragma unroll
    for (int c = 0; c < 4; c++) {
#pragma unroll
        for (int nt = 0; nt < 8; nt++) {
            bf16x8 bb = sB[(nt * 4 + c) * 64 + lane];
            acc[nt] = __builtin_amdgcn_mfma_f32_16x16x32_bf16(ahi[c], bb, acc[nt], 0, 0, 0);
            acc[nt] = __builtin_amdgcn_mfma_f32_16x16x32_bf16(alo[c], bb, acc[nt], 0, 0, 0);
        }
    }

    // C/D: true col = nt*16+qm -> stored col qm*8+nt; row = quad*4+reg
#pragma unroll
    for (int reg = 0; reg < 4; reg++) {
        int orow = r0 + quad * 4 + reg;
        if (orow < nrows) {
            bf16x8 o;
#pragma unroll
            for (int nt = 0; nt < 8; nt++) o[nt] = (__bf16)acc[nt][reg];
            *(bf16x8*)(Zs + (size_t)orow * D + qm * 8) = o;
        }
    }
}

// ------- countb: ONE block per bucket, 1024 threads. Each edge read is useful -------
// (bucket == node range, no filter). R11: partial[] dropped — csr bases derive from
// bucket_cursor prefix (bucket edge count == degree sum of its node range).
__global__ void countb_kernel(const int2* __restrict__ bucket_edges,
                              const int* __restrict__ bucket_cursor,
                              int* __restrict__ counts, float* __restrict__ dinv,
                              int* __restrict__ deghist,
                              int n, int bucketW) {
    __shared__ int bins[1568];
    __shared__ int hb[64];
    int bk = blockIdx.x, t = threadIdx.x;
    int ns = bk * bucketW;
    int ne = min(ns + bucketW, n);
    int w = ne - ns;
    if (w <= 0) return;
    for (int i = t; i < w; i += 1024) bins[i] = 0;
    if (t < 64) hb[t] = 0;
    __syncthreads();
    int m = bucket_cursor[bk];
    const int2* eb = bucket_edges + (size_t)bk * BCAP;
    for (int i = t; i < m; i += 1024) {
        atomicAdd(&bins[eb[i].y - ns], 1);
    }
    __syncthreads();
    for (int i = t; i < w; i += 1024) {
        int c = bins[i];
        counts[ns + i] = c;
        dinv[ns + i] = rsqrtf((float)(c + 1));  // +1 self loop
        atomicAdd(&hb[min(c, 63)], 1);
    }
    __syncthreads();
    if (t < 64 && hb[t]) atomicAdd(&deghist[t], hb[t]);
}

// ------- fillb (R11): ONE block per bucket, 1024 threads. csr segment built in LDS -------
// (LDS atomic scatter) then streamed to global COALESCED — replaces 640k random 4B
// global writes (~41MB effective) with 2.5MB sequential. csr base = bucket_cursor
// exclusive prefix (inline 64-scan). Degree-order scatter unchanged.
__global__ void fillb_kernel(const int2* __restrict__ bucket_edges,
                             const int* __restrict__ bucket_cursor,
                             const int* __restrict__ counts,
                             const int* __restrict__ deghist,
                             int* __restrict__ row_ptr, int* __restrict__ csr,
                             int* __restrict__ degcur, int* __restrict__ order,
                             int n, int bucketW) {
    __shared__ int csr_lds[CSRCAP];   // 48 KB
    __shared__ int cur[1568];
    __shared__ int sm[1024];
    __shared__ int hb2[64];
    __shared__ int gb2[64];
    __shared__ int dgex[64];
    __shared__ int ebase_s;
    int bk = blockIdx.x, t = threadIdx.x;
    int ns = bk * bucketW;
    int ne = min(ns + bucketW, n);
    int w = ne - ns;
    if (w <= 0) return;
    // ---- csr base: inline exclusive scan of bucket_cursor[64] ----
    int bc = (t < 64) ? bucket_cursor[t] : 0;
    sm[t] = bc; __syncthreads();
    for (int off = 1; off < 64; off <<= 1) {
        int u = (t >= off && t < 64) ? sm[t - off] : 0;
        __syncthreads();
        if (t < 64) sm[t] += u;
        __syncthreads();
    }
    if (t == bk) ebase_s = sm[t] - bc;
    __syncthreads();
    int ebase = ebase_s;
    // ---- inline exclusive scan of deghist[64] ----
    int dh = (t < 64) ? deghist[t] : 0;
    sm[t] = dh; __syncthreads();
    for (int off = 1; off < 64; off <<= 1) {
        int u = (t >= off && t < 64) ? sm[t - off] : 0;
        __syncthreads();
        if (t < 64) sm[t] += u;
        __syncthreads();
    }
    if (t < 64) { dgex[t] = sm[t] - dh; hb2[t] = 0; }
    __syncthreads();
    // ---- counts scan (pairs; 1024 threads cover 2048 >= w); offsets LOCAL to bucket ----
    int i0 = t * 2;
    int c0 = (i0 < w) ? counts[ns + i0] : 0;
    int c1 = (i0 + 1 < w) ? counts[ns + i0 + 1] : 0;
    sm[t] = c0 + c1; __syncthreads();
    int own = c0 + c1;
    for (int off = 1; off < 1024; off <<= 1) {
        int u = (t >= off) ? sm[t - off] : 0;
        __syncthreads();
        sm[t] += u;
        __syncthreads();
    }
    int lbase = sm[t] - own;   // local (within-bucket) csr offset
    if (i0 < w)     { row_ptr[ns + i0] = ebase + lbase;          cur[i0] = lbase; }
    if (i0 + 1 < w) { row_ptr[ns + i0 + 1] = ebase + lbase + c0; cur[i0 + 1] = lbase + c0; }
    // degree-order: local ranks within block per bin
    int bin0 = min(c0, 63), bin1 = min(c1, 63);
    int r0 = (i0 < w) ? atomicAdd(&hb2[bin0], 1) : 0;
    int r1 = (i0 + 1 < w) ? atomicAdd(&hb2[bin1], 1) : 0;
    __syncthreads();
    if (t < 64 && hb2[t]) gb2[t] = atomicAdd(&degcur[t], hb2[t]);
    __syncthreads();
    if (i0 < w)     order[dgex[bin0] + gb2[bin0] + r0] = ns + i0;
    if (i0 + 1 < w) order[dgex[bin1] + gb2[bin1] + r1] = ns + i0 + 1;
    __syncthreads();
    int m = bucket_cursor[bk];
    const int2* eb = bucket_edges + (size_t)bk * BCAP;
    if (m <= CSRCAP) {
        // LDS-staged scatter + coalesced flush
        for (int i = t; i < m; i += 1024) {
            int2 ed = eb[i];
            int pos = atomicAdd(&cur[ed.y - ns], 1);
            csr_lds[pos] = ed.x;
        }
        __syncthreads();
        for (int i = t; i < m; i += 1024) csr[ebase + i] = csr_lds[i];
    } else {
        // fallback: direct global scatter (statistically unreachable at these sizes)
        for (int i = t; i < m; i += 1024) {
            int2 ed = eb[i];
            int pos = atomicAdd(&cur[ed.y - ns], 1);
            csr[ebase + pos] = ed.x;
        }
    }
}

// ------- fused agg1 + gemm2: block owns 32 consecutive order-slots, HEAVY-FIRST. -------
// Phase A: H = relu(dinv^2*Z1[v] + sum w*Z1[s] + b1) -> LDS (XOR-swizzled 16B slots),
//   4-deep csr prefetch breaking the csr->row serial latency chain (R3 form, 43.6 us).
// Phase B: Z2'[v] = dinv[v] * (H @ W2), W2 staged in 4 x 8KB rounds (16KB LDS total).
__global__ void agg1_gemm2_kernel(const __bf16* __restrict__ Zs, const int* __restrict__ row_ptr,
                                  const int* __restrict__ counts, const int* __restrict__ csr,
                                  const float* __restrict__ dinv, const float* __restrict__ bias,
                                  const __bf16* __restrict__ PW, const int* __restrict__ order,
                                  __bf16* __restrict__ Z2, int n) {
    __shared__ __align__(16) __bf16 sH[32 * 128];  // 8 KB
    __shared__ bf16x8 sBp[512];                    // 8 KB (one k-chunk of packed W2)
    int t = threadIdx.x;  // 0..127
    const bf16x8* PW8 = (const bf16x8*)PW;

    int gbase = blockIdx.x * 32;
    int grp = t >> 4, c = t & 15;

    // hoist bias for this lane's 8 stored cols (true col j*16+c)
    float bs[8];
#pragma unroll
    for (int j = 0; j < 8; j++) bs[j] = bias[j * 16 + c];

    const bf16x8* Z8 = (const bf16x8*)Zs;
    for (int r = 0; r < 4; r++) {
        int lr = r * 8 + grp;           // local row 0..31
        int idx = gbase + lr;
        bf16x8 o = {};
        if (idx < n) {
            int v = order[(n - 1) - idx];   // heavy-first
            float dv = dinv[v];
            bf16x8 zc = Z8[(size_t)v * 16 + c];
            float sw = dv * dv;
            float acc[8];
#pragma unroll
            for (int j = 0; j < 8; j++) acc[j] = (float)zc[j] * sw;
            int start = row_ptr[v], cnt = counts[v];
            int i = 0;
            if (cnt >= 4) {
                int s0 = csr[start], s1 = csr[start + 1];
                int s2 = csr[start + 2], s3 = csr[start + 3];
                for (; i + 8 <= cnt; i += 4) {
                    int t0 = csr[start + i + 4], t1 = csr[start + i + 5];
                    int t2 = csr[start + i + 6], t3 = csr[start + i + 7];
                    bf16x8 m0 = Z8[(size_t)s0 * 16 + c];
                    bf16x8 m1 = Z8[(size_t)s1 * 16 + c];
                    bf16x8 m2 = Z8[(size_t)s2 * 16 + c];
                    bf16x8 m3 = Z8[(size_t)s3 * 16 + c];
                    float w0 = dinv[s0] * dv, w1 = dinv[s1] * dv;
                    float w2 = dinv[s2] * dv, w3 = dinv[s3] * dv;
#pragma unroll
                    for (int j = 0; j < 8; j++) acc[j] = fmaf(w0, (float)m0[j], acc[j]);
#pragma unroll
                    for (int j = 0; j < 8; j++) acc[j] = fmaf(w1, (float)m1[j], acc[j]);
#pragma unroll
                    for (int j = 0; j < 8; j++) acc[j] = fmaf(w2, (float)m2[j], acc[j]);
#pragma unroll
                    for (int j = 0; j < 8; j++) acc[j] = fmaf(w3, (float)m3[j], acc[j]);
                    s0 = t0; s1 = t1; s2 = t2; s3 = t3;
                }
                {   // drain the prefetched quad
                    bf16x8 m0 = Z8[(size_t)s0 * 16 + c];
                    bf16x8 m1 = Z8[(size_t)s1 * 16 + c];
                    bf16x8 m2 = Z8[(size_t)s2 * 16 + c];
                    bf16x8 m3 = Z8[(size_t)s3 * 16 + c];
                    float w0 = dinv[s0] * dv, w1 = dinv[s1] * dv;
                    float w2 = dinv[s2] * dv, w3 = dinv[s3] * dv;
#pragma unroll
                    for (int j = 0; j < 8; j++) acc[j] = fmaf(w0, (float)m0[j], acc[j]);
#pragma unroll
                    for (int j = 0; j < 8; j++) acc[j] = fmaf(w1, (float)m1[j], acc[j]);
#pragma unroll
                    for (int j = 0; j < 8; j++) acc[j] = fmaf(w2, (float)m2[j], acc[j]);
#pragma unroll
                    for (int j = 0; j < 8; j++) acc[j] = fmaf(w3, (float)m3[j], acc[j]);
                    i += 4;
                }
            }
            for (; i < cnt; i++) {
                int s0 = csr[start + i];
                float w0 = dinv[s0] * dv;
                bf16x8 m0 = Z8[(size_t)s0 * 16 + c];
#pragma unroll
                for (int j = 0; j < 8; j++) acc[j] = fmaf(w0, (float)m0[j], acc[j]);
            }
#pragma unroll
            for (int j = 0; j < 8; j++) o[j] = (__bf16)fmaxf(acc[j] + bs[j], 0.f);
        }
        // swizzled 16B-slot write: slot c -> c ^ (lr&7)
        *(bf16x8*)(sH + lr * 128 + ((c ^ (lr & 7)) << 3)) = o;
    }

    // ---- phase B: 4 rounds; each stages 8KB of W2 (k-chunk cc) then 8 MFMAs ----
    int wave = t >> 6, lane = t & 63;
    int qm = lane & 15, quad = lane >> 4;
    int lrow = wave * 16 + qm;

    f32x4 acc[8];
#pragma unroll
    for (int nt = 0; nt < 8; nt++) acc[nt] = (f32x4){0.f, 0.f, 0.f, 0.f};

#pragma unroll
    for (int cc = 0; cc < 4; cc++) {
        __syncthreads();  // round cc-1 reads done (and, at cc=0, all sH writes visible)
#pragma unroll
        for (int i = 0; i < 4; i++) {
            int idx = i * 128 + t;  // 0..511
            sBp[idx] = PW8[((idx >> 6) * 4 + cc) * 64 + (idx & 63)];
        }
        // A-fragment for this k-chunk from swizzled sH (overlaps with sBp stage)
        int slot = quad + cc * 4;  // 16B slot index within the 256B row
        bf16x8 a = *(const bf16x8*)(sH + lrow * 128 + ((slot ^ (lrow & 7)) << 3));
        __syncthreads();  // sBp visible
#pragma unroll
        for (int nt = 0; nt < 8; nt++) {
            bf16x8 bb = sBp[nt * 64 + lane];
            acc[nt] = __builtin_amdgcn_mfma_f32_16x16x32_bf16(a, bb, acc[nt], 0, 0, 0);
        }
    }

    // C/D: true col = nt*16+qm -> stored col qm*8+nt; local row = wave*16 + quad*4 + reg
#pragma unroll
    for (int reg = 0; reg < 4; reg++) {
        int lrr = wave * 16 + quad * 4 + reg;
        int gidx = gbase + lrr;
        if (gidx < n) {
            int v = order[(n - 1) - gidx];  // heavy-first (must match phase A mapping)
            float sc = dinv[v];  // prescale: Z2' = dinv[v] * Z2
            bf16x8 o;
#pragma unroll
            for (int nt = 0; nt < 8; nt++) o[nt] = (__bf16)(acc[nt][reg] * sc);
            *(bf16x8*)(Z2 + (size_t)v * D + qm * 8) = o;
        }
    }
}

// ------- agg2 + fc fused (heavy-first, Z2 PRESCALED by dinv): -------
// out[v] = relu(dinv_v * (sum_s Z2'[s] + Z2'[v]) + b2) @ Wfc + bfc
__global__ void agg2_fc_kernel(const __bf16* __restrict__ Zs, const int* __restrict__ row_ptr,
                               const int* __restrict__ counts, const int* __restrict__ csr,
                               const float* __restrict__ dinv, const float* __restrict__ bias,
                               const float* __restrict__ Wfc, const float* __restrict__ bfc,
                               const int* __restrict__ order, float* __restrict__ out, int n) {
    int t = blockIdx.x * 256 + threadIdx.x;
    int idx = t >> 4, c = t & 15;
    if (idx >= n) return;
    int v = order[(n - 1) - idx];   // heavy-first
    float dv = dinv[v];
    const bf16x8* Z8 = (const bf16x8*)Zs;
    bf16x8 zc = Z8[(size_t)v * 16 + c];  // self term: dinv_v^2 Z2[v] = dinv_v * Z2'[v]
    float acc[8];
#pragma unroll
    for (int j = 0; j < 8; j++) acc[j] = (float)zc[j];
    int start = row_ptr[v], cnt = counts[v];
    int i = 0;
    if (cnt >= 4) {
        int s0 = csr[start], s1 = csr[start + 1];
        int s2 = csr[start + 2], s3 = csr[start + 3];
        for (; i + 8 <= cnt; i += 4) {
            int t0 = csr[start + i + 4], t1 = csr[start + i + 5];
            int t2 = csr[start + i + 6], t3 = csr[start + i + 7];
            bf16x8 m0 = Z8[(size_t)s0 * 16 + c];
            bf16x8 m1 = Z8[(size_t)s1 * 16 + c];
            bf16x8 m2 = Z8[(size_t)s2 * 16 + c];
            bf16x8 m3 = Z8[(size_t)s3 * 16 + c];
#pragma unroll
            for (int j = 0; j < 8; j++) acc[j] += (float)m0[j];
#pragma unroll
            for (int j = 0; j < 8; j++) acc[j] += (float)m1[j];
#pragma unroll
            for (int j = 0; j < 8; j++) acc[j] += (float)m2[j];
#pragma unroll
            for (int j = 0; j < 8; j++) acc[j] += (float)m3[j];
            s0 = t0; s1 = t1; s2 = t2; s3 = t3;
        }
        {
            bf16x8 m0 = Z8[(size_t)s0 * 16 + c];
            bf16x8 m1 = Z8[(size_t)s1 * 16 + c];
            bf16x8 m2 = Z8[(size_t)s2 * 16 + c];
            bf16x8 m3 = Z8[(size_t)s3 * 16 + c];
#pragma unroll
            for (int j = 0; j < 8; j++) acc[j] += (float)m0[j];
#pragma unroll
            for (int j = 0; j < 8; j++) acc[j] += (float)m1[j];
#pragma unroll
            for (int j = 0; j < 8; j++) acc[j] += (float)m2[j];
#pragma unroll
            for (int j = 0; j < 8; j++) acc[j] += (float)m3[j];
            i += 4;
        }
    }
    for (; i < cnt; i++) {
        int s0 = csr[start + i];
        bf16x8 m0 = Z8[(size_t)s0 * 16 + c];
#pragma unroll
        for (int j = 0; j < 8; j++) acc[j] += (float)m0[j];
    }
    float a0 = 0.f, a1 = 0.f;
#pragma unroll
    for (int j = 0; j < 8; j++) {
        int p = j * 16 + c;  // true col
        float hj = fmaxf(fmaf(dv, acc[j], bias[p]), 0.f);
        a0 = fmaf(hj, Wfc[p * 2], a0);
        a1 = fmaf(hj, Wfc[p * 2 + 1], a1);
    }
#pragma unroll
    for (int off = 8; off > 0; off >>= 1) {
        a0 += __shfl_down(a0, off, 16);
        a1 += __shfl_down(a1, off, 16);
    }
    if (c == 0) {
        out[(size_t)v * 2 + 0] = a0 + bfc[0];
        out[(size_t)v * 2 + 1] = a1 + bfc[1];
    }
}

// ---------------- launch ----------------

extern "C" void kernel_launch(void* const* d_in, const int* in_sizes, int n_in,
                              void* d_out, int out_size, void* d_ws, size_t ws_size,
                              hipStream_t stream) {
    const float* x   = (const float*)d_in[0];
    const int*   ei  = (const int*)d_in[1];
    const float* W1  = (const float*)d_in[2];
    const float* b1  = (const float*)d_in[3];
    const float* W2  = (const float*)d_in[4];
    const float* b2  = (const float*)d_in[5];
    const float* Wfc = (const float*)d_in[6];
    const float* bfc = (const float*)d_in[7];
    float* out = (float*)d_out;

    int n = in_sizes[0] / D;   // 100000
    int e = in_sizes[1] / 2;   // 640000
    const int* src = ei;
    const int* dst = ei + e;

    int bucketW = (n + NBUCKET - 1) / NBUCKET;   // 1563 (<= 1568 LDS bins)

    // workspace layout (16B-aligned at these sizes)
    char* ws = (char*)d_ws;
    size_t nb = (size_t)n * 4;
    int*    counts  = (int*)(ws);
    float*  dinv    = (float*)(ws + nb);
    int*    rowptr  = (int*)(ws + 2 * nb);
    int*    partial = (int*)(ws + 3 * nb);                    // 1024 B (unused, kept for layout)
    int*    bcur    = (int*)(ws + 3 * nb + 1024);             // 256 B
    int*    deghist = (int*)(ws + 3 * nb + 1280);             // 256 B
    int*    degcur  = (int*)(ws + 3 * nb + 1536);             // 256 B (+256 pad)
    int*    order   = (int*)(ws + 3 * nb + 2048);             // n*4
    int2*   bedges  = (int2*)(ws + 4 * nb + 2048);            // 8 MB
    size_t  off1    = 4 * nb + 2048 + (size_t)NBUCKET * BCAP * 8;
    int*    csr     = (int*)(ws + off1);                      // e*4
    __bf16* pw      = (__bf16*)(ws + off1 + (size_t)e * 4);   // 64 KB packed (W1|W2)
    __bf16* z1      = (__bf16*)(ws + off1 + (size_t)e * 4 + 65536);
    __bf16* z2      = z1 + (size_t)n * D;
    (void)partial;

    int eab = ((e + 3) / 4 + 255) / 256;       // bucketize blocks (625)
    int gb  = (n + 63) / 64;                   // gemm blocks (1563)
    int gb2 = (n + 31) / 32;                   // fused agg1+gemm2 blocks (3125)
    int ab  = ((n * 16) + 255) / 256;          // agg blocks (6250)

    prep_kernel<<<129, 256, 0, stream>>>(W1, W2, pw, bcur, deghist, degcur);
    mega1_kernel<<<gb + eab, 256, 0, stream>>>(x, pw, z1, n, gb, src, dst,
                                               bcur, bedges, e, bucketW);
    countb_kernel<<<NBUCKET, 1024, 0, stream>>>(bedges, bcur, counts, dinv,
                                                deghist, n, bucketW);
    fillb_kernel<<<NBUCKET, 1024, 0, stream>>>(bedges, bcur, counts, deghist,
                                               rowptr, csr, degcur, order, n, bucketW);
    agg1_gemm2_kernel<<<gb2, 128, 0, stream>>>(z1, rowptr, counts, csr, dinv, b1,
                                               pw + 16384, order, z2, n);
    agg2_fc_kernel<<<ab, 256, 0, stream>>>(z2, rowptr, counts, csr, dinv, b2, Wfc, bfc,
                                           order, out, n);
}